// Round 5
// baseline (346.192 us; speedup 1.0000x reference)
//
#include <hip/hip_runtime.h>
#include <math.h>

#define NTOK   16384
#define DDIM   256
#define HWD    1024        // H*W per batch image
#define CHW    262144      // 256*1024 floats per batch
#define MARGIN 1.6e-4f     // bf16 phase-1 error (8 sigma) + ref d-grid + ee span + fp16 quant

// ws layout (bytes)
#define WS_ABF   0u          // 8 MB  bf16 token images [128 tiles][4 chunks][16KB swizzled]
#define WS_BBF   8388608u    // 8 MB  bf16 code  images
#define WS_SUBT  16777216u   // 16 MB fp16 subtile mins: [n>>6][n&63][512 subtiles]
#define WS_EE    33554432u   // 64KB
#define WS_ZZ    33619968u   // 64KB
#define WS_IDX   33685504u   // 64KB
#define WS_CNT   33751040u   // 64KB
#define WS_SUM   33816576u   // 16B (contiguous after counts)

typedef __attribute__((ext_vector_type(8))) short  s8b;    // 8 bf16 (4 VGPR)
typedef __attribute__((ext_vector_type(8))) unsigned short us8;
typedef __attribute__((ext_vector_type(4))) float  f32x4;
typedef __attribute__((ext_vector_type(8))) _Float16 h8;

__device__ __forceinline__ unsigned short f2bf(float f) {
  unsigned int u = __float_as_uint(f);
  return (unsigned short)((u + 0x7fffu + ((u >> 16) & 1u)) >> 16);  // RNE
}

// ---------------- prepA: z (NCHW) -> bf16 token images + zz + zt [n][d] fp32 ----------------
// image layout per (tile,chunk): phys_byte(row,k) = ((row*128 + (k>>3)*16) ^ ((row&7)<<4)) + (k&7)*2
__global__ __launch_bounds__(256) void k_prepA(const float* __restrict__ z,
                                               unsigned short* __restrict__ Abf,
                                               float* __restrict__ zz,
                                               float* __restrict__ zt) {
  __shared__ double part[4][64];
  const int t64 = threadIdx.x & 63, chunk = threadIdx.x >> 6;
  const int n = blockIdx.x * 64 + t64;
  const int b = n >> 10, hw = n & 1023;
  const float* zp = z + (size_t)b * CHW + hw;
  const int row = n & 127, tile = n >> 7;
  char* dst = (char*)Abf + (size_t)tile * 65536 + (size_t)chunk * 16384;
  const int rowoff = row * 128, sw = (row & 7) << 4;
  float* ztp = zt + (size_t)n * 256 + chunk * 64;
  double s = 0.0;
  #pragma unroll
  for (int kb = 0; kb < 8; ++kb) {
    us8 v;
    float tmp[8];
    #pragma unroll
    for (int j = 0; j < 8; ++j) {
      const int d = chunk * 64 + kb * 8 + j;
      const float f = zp[(size_t)d * HWD];
      tmp[j] = f;
      v[j] = f2bf(f);
      s += (double)f * (double)f;                 // d ascending
    }
    *(us8*)(dst + ((rowoff + kb * 16) ^ sw)) = v;
    *(float4*)(ztp + kb * 8)     = *(float4*)&tmp[0];
    *(float4*)(ztp + kb * 8 + 4) = *(float4*)&tmp[4];
  }
  part[chunk][t64] = s;
  __syncthreads();
  if (threadIdx.x < 64)
    zz[n] = (float)(part[0][t64] + part[1][t64] + part[2][t64] + part[3][t64]);
}

// ---------------- prepB: emb -> bf16 code images + ee (coalesced via LDS transpose) ----------------
__global__ __launch_bounds__(256) void k_prepB(const float* __restrict__ emb,
                                               unsigned short* __restrict__ Bbf,
                                               float* __restrict__ ee) {
  __shared__ float rows[64][257];   // +1 pad: lanes span (t64+d)%32 -> 2-way, free
  __shared__ double part[4][64];
  const int tid = threadIdx.x;
  const int k0 = blockIdx.x * 64;
  for (int i = tid; i < 16384; i += 256)          // coalesced: lane = d
    rows[i >> 8][i & 255] = emb[(size_t)k0 * DDIM + i];
  __syncthreads();
  const int t64 = tid & 63, chunk = tid >> 6;
  const int code = k0 + t64;
  const int row = code & 127, tile = code >> 7;
  char* dst = (char*)Bbf + (size_t)tile * 65536 + (size_t)chunk * 16384;
  const int rowoff = row * 128, sw = (row & 7) << 4;
  double s = 0.0;
  #pragma unroll
  for (int kb = 0; kb < 8; ++kb) {
    us8 v;
    #pragma unroll
    for (int j = 0; j < 8; ++j) {
      const float f = rows[t64][chunk * 64 + kb * 8 + j];
      v[j] = f2bf(f);
      s += (double)f * (double)f;
    }
    *(us8*)(dst + ((rowoff + kb * 16) ^ sw)) = v;
  }
  part[chunk][t64] = s;
  __syncthreads();
  if (tid < 64)
    ee[code] = (float)(part[0][t64] + part[1][t64] + part[2][t64] + part[3][t64]);
}

// ---------------- phase-1: 256x256 GEMM-min, counted-vmcnt 2-deep pipeline ----------------
// grid 4096 = 64 token-groups x 64 code-groups; 512 thr = 8 waves (2 code-halves x 4 token-qtrs).
// Wave: 128 codes x 64 tokens via 8x4 frags of mfma_f32_16x16x32_bf16 (A=codes: C row=code, col=token).
// K=256 in 4 chunks of 64. Schedule per chunk: {ds_read all frags -> regs; lgkm0+barrier;
// STAGE(kc+2) into the now-dead current buffer; MFMA x64 (setprio); vmcnt(8)+barrier}.
// vmcnt never drains to 0 until the tail (T4); 8 global_load_lds per wave per STAGE.
__global__ __launch_bounds__(512, 2) void k_mdist(
    const unsigned short* __restrict__ tokimg, const unsigned short* __restrict__ codimg,
    _Float16* __restrict__ subt) {
  __shared__ __attribute__((aligned(16))) char lds[131072];   // 2 x (32KB A + 32KB B)
  const int raw = blockIdx.x;
  // XCD p owns code-groups p*8..p*8+7 (1MB, L2-fit); 8x8 (tg x cg) supertiles inside.
  const int p = raw & 7, local = raw >> 3;
  const int st = local >> 6, q = local & 63;
  const int cg = p * 8 + (q >> 3);        // 0..63: codes cg*256
  const int tg = st * 8 + (q & 7);        // 0..63: tokens tg*256
  const int tid = threadIdx.x;
  const int w = tid >> 6, lane = tid & 63;
  const int cm = w >> 2, tn = w & 3;      // code-half, token-quarter
  const int fr = lane & 15, fq = lane >> 4;

  const char* asrc = (const char*)codimg + (size_t)(2 * cg) * 65536;  // codes  (A)
  const char* bsrc = (const char*)tokimg + (size_t)(2 * tg) * 65536;  // tokens (B)

  int aoff[8][2], boff[4][2];
  #pragma unroll
  for (int m = 0; m < 8; ++m)
    #pragma unroll
    for (int ks = 0; ks < 2; ++ks) {
      const int c = cm * 128 + m * 16 + fr;
      const int rl = c & 127;
      aoff[m][ks] = (c >> 7) * 16384 + ((rl * 128 + (ks * 4 + fq) * 16) ^ ((rl & 7) << 4));
    }
  #pragma unroll
  for (int n = 0; n < 4; ++n)
    #pragma unroll
    for (int ks = 0; ks < 2; ++ks) {
      const int t = tn * 64 + n * 16 + fr;
      const int rl = t & 127;
      boff[n][ks] = 32768 + (t >> 7) * 16384 + ((rl * 128 + (ks * 4 + fq) * 16) ^ ((rl & 7) << 4));
    }

  f32x4 acc[8][4];
  #pragma unroll
  for (int m = 0; m < 8; ++m)
    #pragma unroll
    for (int n = 0; n < 4; ++n) acc[m][n] = (f32x4)0.0f;

  // stage one K-chunk (A 32KB + B 32KB) into buffer `buf`: 8 loads per thread
  #define STAGE(buf, kc)                                                              \
    {                                                                                 \
      char* dstb = lds + (buf) * 65536;                                               \
      _Pragma("unroll")                                                               \
      for (int r = 0; r < 4; ++r) {                                                   \
        const int u = r * 512 + w * 64 + lane;                                        \
        const int si = u >> 10, off = (u & 1023) * 16;                                \
        __builtin_amdgcn_global_load_lds(                                             \
          (const __attribute__((address_space(1))) void*)(asrc + (size_t)si * 65536 + (kc) * 16384 + off), \
          (__attribute__((address_space(3))) void*)(dstb + u * 16), 16, 0, 0);        \
      }                                                                               \
      _Pragma("unroll")                                                               \
      for (int r = 0; r < 4; ++r) {                                                   \
        const int u = r * 512 + w * 64 + lane;                                        \
        const int si = u >> 10, off = (u & 1023) * 16;                                \
        __builtin_amdgcn_global_load_lds(                                             \
          (const __attribute__((address_space(1))) void*)(bsrc + (size_t)si * 65536 + (kc) * 16384 + off), \
          (__attribute__((address_space(3))) void*)(dstb + 32768 + u * 16), 16, 0, 0); \
      }                                                                               \
    }

  STAGE(0, 0);
  STAGE(1, 1);
  asm volatile("s_waitcnt vmcnt(8)" ::: "memory");   // oldest 8 (=buf0) landed
  __builtin_amdgcn_s_barrier();
  __builtin_amdgcn_sched_barrier(0);

  #pragma unroll
  for (int kc = 0; kc < 4; ++kc) {
    const char* bufb = lds + (kc & 1) * 65536;
    s8b a[8][2], b[4][2];
    #pragma unroll
    for (int ks = 0; ks < 2; ++ks) {
      #pragma unroll
      for (int m = 0; m < 8; ++m) a[m][ks] = *(const s8b*)(bufb + aoff[m][ks]);
      #pragma unroll
      for (int n = 0; n < 4; ++n) b[n][ks] = *(const s8b*)(bufb + boff[n][ks]);
    }
    if (kc < 2) {
      // certify all waves' reads of this buffer done, then overwrite it with kc+2
      asm volatile("s_waitcnt lgkmcnt(0)" ::: "memory");
      __builtin_amdgcn_sched_barrier(0);
      __builtin_amdgcn_s_barrier();
      __builtin_amdgcn_sched_barrier(0);
      STAGE(kc & 1, kc + 2);
    }
    __builtin_amdgcn_s_setprio(1);
    #pragma unroll
    for (int ks = 0; ks < 2; ++ks)
      #pragma unroll
      for (int m = 0; m < 8; ++m)
        #pragma unroll
        for (int n = 0; n < 4; ++n)
          acc[m][n] = __builtin_amdgcn_mfma_f32_16x16x32_bf16(a[m][ks], b[n][ks], acc[m][n], 0, 0, 0);
    __builtin_amdgcn_s_setprio(0);
    if (kc < 2) {
      asm volatile("s_waitcnt vmcnt(8)" ::: "memory");   // next buffer's 8 landed
      __builtin_amdgcn_s_barrier();
      __builtin_amdgcn_sched_barrier(0);
    } else if (kc == 2) {
      asm volatile("s_waitcnt vmcnt(0)" ::: "memory");   // tail: last chunk landed
      __builtin_amdgcn_s_barrier();
      __builtin_amdgcn_sched_barrier(0);
    }
  }

  // epilogue: per-token max per 32-code subtile (codes on reg+fq axis -> cheap).
  // outT aliases lds[0..4KB] (buf0): last buf0 reads were fenced at kc=2's barriers.
  _Float16* outT = (_Float16*)lds;          // [256 tokens][8 subtiles]
  #pragma unroll
  for (int s = 0; s < 4; ++s) {
    #pragma unroll
    for (int n = 0; n < 4; ++n) {
      float v = acc[2 * s][n][0];
      #pragma unroll
      for (int j = 1; j < 4; ++j) v = fmaxf(v, acc[2 * s][n][j]);
      #pragma unroll
      for (int j = 0; j < 4; ++j) v = fmaxf(v, acc[2 * s + 1][n][j]);
      v = fmaxf(v, __shfl_xor(v, 16, 64));  // fold fq bit0
      v = fmaxf(v, __shfl_xor(v, 32, 64));  // fold fq bit1 -> max over all 32 codes
      if (lane < 16)
        outT[(tn * 64 + n * 16 + fr) * 8 + cm * 4 + s] = (_Float16)(-2.0f * v);
    }
  }
  __syncthreads();
  if (tid < 256) {
    const int t = tid;                      // token n = tg*256 + t
    _Float16* g = subt + (size_t)(tg * 4 + (t >> 6)) * 32768 + (size_t)(t & 63) * 512 + cg * 8;
    *(h8*)g = *(const h8*)(outT + t * 8);
  }
}

// ---------------- phase-2: exact re-check of candidate subtiles, argmin (8 tokens/block) ----------------
__global__ __launch_bounds__(256) void k_pick(
    const float* __restrict__ zt, const float* __restrict__ emb,
    const float* __restrict__ zz, const float* __restrict__ ee,
    const _Float16* __restrict__ subt, int* __restrict__ idx,
    float* __restrict__ out_idxf) {
  __shared__ float zrow[256];
  __shared__ int clist[512];
  __shared__ int ccnt;
  __shared__ float wm[4];
  __shared__ unsigned long long bests[16];
  const int tid = threadIdx.x;
  const int w = tid >> 6, lane = tid & 63;
  const int g16 = lane >> 4, l16 = lane & 15;
  for (int ni = 0; ni < 8; ++ni) {
    const int n = blockIdx.x * 8 + ni;
    __syncthreads();                          // protect shared reuse across tokens
    if (tid == 0) ccnt = 0;
    zrow[tid] = zt[(size_t)n * 256 + tid];    // coalesced row
    const _Float16* tp = subt + (size_t)(n >> 6) * 32768 + (size_t)(n & 63) * 512;
    const float ta = (float)tp[tid];
    const float tb = (float)tp[tid + 256];
    float m2 = fminf(ta, tb);
    #pragma unroll
    for (int o = 32; o; o >>= 1) m2 = fminf(m2, __shfl_xor(m2, o, 64));
    if (lane == 0) wm[w] = m2;
    __syncthreads();
    const float thr = fminf(fminf(wm[0], wm[1]), fminf(wm[2], wm[3])) + MARGIN;
    if (ta <= thr) { int pp = atomicAdd(&ccnt, 1); clist[pp] = tid; }
    if (tb <= thr) { int pp = atomicAdd(&ccnt, 1); clist[pp] = tid + 256; }
    __syncthreads();
    const int nc = ccnt;
    const float zzn = zz[n];
    unsigned long long best = ~0ull;
    for (int ci = 0; ci < nc; ++ci) {
      const int t = clist[ci];               // candidate subtile (any order: min is total)
      #pragma unroll
      for (int pc = 0; pc < 2; ++pc) {
        const int k = t * 32 + w * 8 + pc * 4 + g16;   // 16 lanes per code
        const float* er = emb + (size_t)k * DDIM;
        double s = 0.0;
        #pragma unroll
        for (int qq = 0; qq < 4; ++qq) {
          const float4 ev = *(const float4*)(er + qq * 64 + l16 * 4);   // coalesced 256B
          const float4 zv = *(const float4*)(&zrow[qq * 64 + l16 * 4]);
          s += (double)zv.x * (double)ev.x + (double)zv.y * (double)ev.y
             + (double)zv.z * (double)ev.z + (double)zv.w * (double)ev.w;
        }
        #pragma unroll
        for (int o = 8; o; o >>= 1) s += __shfl_xor(s, o, 16);
        if (l16 == 0) {
          const float mm = (float)s;                   // exact dot -> one fp32 rounding
          const float d = (zzn + ee[k]) - 2.0f * mm;   // replicate ref quantization (d > 0)
          const unsigned long long c =
              ((unsigned long long)__float_as_uint(d) << 32) | (unsigned int)k;
          if (c < best) best = c;                      // lexicographic (d, k)
        }
      }
    }
    if (l16 == 0) bests[w * 4 + g16] = best;
    __syncthreads();
    if (tid == 0) {
      unsigned long long bb = bests[0];
      #pragma unroll
      for (int i = 1; i < 16; ++i) bb = bests[i] < bb ? bests[i] : bb;
      const int k0 = (int)(bb & 0xffffffffu);
      idx[n] = k0;
      out_idxf[n] = (float)k0;
    }
  }
}

// ---------------- scatter z_q (coalesced), loss partial, counts ----------------
__global__ __launch_bounds__(256) void k_scatter(
    const float* __restrict__ z, const float* __restrict__ emb,
    const int* __restrict__ idx, float* __restrict__ out_zq,
    int* __restrict__ counts, double* __restrict__ sums) {
  __shared__ float et[64][257];   // 64 tokens x 256 dims, pad 257
  __shared__ int sidx[64];
  __shared__ double w4[4];
  const int tg = blockIdx.x;      // 256 groups of 64 tokens
  const int n0 = tg * 64;
  const int b = n0 >> 10, hw0 = n0 & 1023;
  const int tid = threadIdx.x;
  if (tid < 64) sidx[tid] = idx[n0 + tid];
  __syncthreads();
  for (int i = tid; i < 16384; i += 256) {      // gather code rows (coalesced along d)
    const int t = i >> 8, d = i & 255;
    et[t][d] = emb[(size_t)sidx[t] * DDIM + d];
  }
  __syncthreads();
  const float* zb = z + (size_t)b * CHW + hw0;
  float* ob = out_zq + (size_t)b * CHW + hw0;
  double s = 0.0;
  for (int i = tid; i < 16384; i += 256) {      // NCHW order: coalesced z reads + zq writes
    const int d = i >> 6, t = i & 63;
    const float v = et[t][d];
    const float diff = v - zb[(size_t)d * HWD + t];
    ob[(size_t)d * HWD + t] = v;                // z_q_st == z_q numerically
    s += (double)diff * (double)diff;
  }
  #pragma unroll
  for (int o = 32; o; o >>= 1) s += __shfl_xor(s, o, 64);
  const int wd = tid >> 6, lane = tid & 63;
  if (lane == 0) w4[wd] = s;
  __syncthreads();
  if (tid == 0) atomicAdd(&sums[0], w4[0] + w4[1] + w4[2] + w4[3]);
  if (tid < 64) atomicAdd(&counts[sidx[tid]], 1);
}

// ---------------- entropy partial from counts ----------------
__global__ __launch_bounds__(256) void k_hist(const int* __restrict__ counts,
                                              double* __restrict__ sums) {
  const int i = blockIdx.x * 256 + threadIdx.x;
  const float em = (float)counts[i] * (1.0f / 16384.0f);
  const float term = em * logf(em + 1e-10f);
  double s = (double)term;
  #pragma unroll
  for (int o = 32; o; o >>= 1) s += __shfl_xor(s, o, 64);
  __shared__ double w4[4];
  const int wid = threadIdx.x >> 6, lane = threadIdx.x & 63;
  if (lane == 0) w4[wid] = s;
  __syncthreads();
  if (threadIdx.x == 0) atomicAdd(&sums[1], w4[0] + w4[1] + w4[2] + w4[3]);
}

// ---------------- finals ----------------
__global__ void k_final(const double* __restrict__ sums,
                        float* __restrict__ out_loss,
                        float* __restrict__ out_perp) {
  if (threadIdx.x == 0) {
    out_loss[0] = (float)(1.25 * sums[0] / 4194304.0);  // (1+BETA)*mean
    out_perp[0] = (float)exp(-sums[1]);
  }
}

extern "C" void kernel_launch(void* const* d_in, const int* in_sizes, int n_in,
                              void* d_out, int out_size, void* d_ws, size_t ws_size,
                              hipStream_t stream) {
  const float* z   = (const float*)d_in[0];   // [16,256,32,32]
  const float* emb = (const float*)d_in[1];   // [16384,256]
  float* out      = (float*)d_out;
  float* out_zq   = out;                      // 4194304
  float* out_loss = out + 4194304;
  float* out_perp = out + 4194305;
  float* out_idxf = out + 4194306;            // 16384 (idx as float)
  float* zt       = out;                      // [n][d] fp32 transpose; dead before k_scatter overwrites

  char* ws = (char*)d_ws;
  unsigned short* Abf = (unsigned short*)(ws + WS_ABF);
  unsigned short* Bbf = (unsigned short*)(ws + WS_BBF);
  _Float16* subt  = (_Float16*)(ws + WS_SUBT);
  float*  ee      = (float*)(ws + WS_EE);
  float*  zz      = (float*)(ws + WS_ZZ);
  int*    idx     = (int*)  (ws + WS_IDX);
  int*    counts  = (int*)  (ws + WS_CNT);
  double* sums    = (double*)(ws + WS_SUM);

  hipMemsetAsync(counts, 0, 65536 + 16, stream);

  k_prepA<<<256, 256, 0, stream>>>(z, Abf, zz, zt);
  k_prepB<<<256, 256, 0, stream>>>(emb, Bbf, ee);
  k_mdist<<<4096, 512, 0, stream>>>(Abf, Bbf, subt);
  k_pick <<<2048, 256, 0, stream>>>(zt, emb, zz, ee, subt, idx, out_idxf);
  k_scatter<<<256, 256, 0, stream>>>(z, emb, idx, out_zq, counts, sums);
  k_hist <<<64, 256, 0, stream>>>(counts, sums);
  k_final<<<1, 64, 0, stream>>>(sums, out_loss, out_perp);
}

// Round 6
// 342.178 us; speedup vs baseline: 1.0117x; 1.0117x over previous
//
#include <hip/hip_runtime.h>
#include <math.h>

#define NTOK   16384
#define DDIM   256
#define HWD    1024        // H*W per batch image
#define CHW    262144      // 256*1024 floats per batch
#define MARGIN 1.6e-4f     // bf16 phase-1 error (8 sigma) + ref d-grid + ee span + fp16 quant

// ws layout (bytes)
#define WS_ABF   0u          // 8 MB  bf16 token images [128 tiles][4 chunks][16KB swizzled]
#define WS_BBF   8388608u    // 8 MB  bf16 code  images
#define WS_SUBT  16777216u   // 16 MB fp16 subtile mins: [n>>6][n&63][512 subtiles]
#define WS_EE    33554432u   // 64KB
#define WS_ZZ    33619968u   // 64KB
#define WS_IDX   33685504u   // 64KB
#define WS_CNT   33751040u   // 64KB
#define WS_SUM   33816576u   // 16B (contiguous after counts)

typedef __attribute__((ext_vector_type(8))) short  s8b;    // 8 bf16 (4 VGPR)
typedef __attribute__((ext_vector_type(8))) unsigned short us8;
typedef __attribute__((ext_vector_type(4))) float  f32x4;
typedef __attribute__((ext_vector_type(8))) _Float16 h8;

__device__ __forceinline__ unsigned short f2bf(float f) {
  unsigned int u = __float_as_uint(f);
  return (unsigned short)((u + 0x7fffu + ((u >> 16) & 1u)) >> 16);  // RNE
}

// ---------------- prepA: z (NCHW) -> bf16 token images + zz + zt [n][d] fp32 ----------------
// image layout per (tile,chunk): phys_byte(row,k) = ((row*128 + (k>>3)*16) ^ ((row&7)<<4)) + (k&7)*2
__global__ __launch_bounds__(256) void k_prepA(const float* __restrict__ z,
                                               unsigned short* __restrict__ Abf,
                                               float* __restrict__ zz,
                                               float* __restrict__ zt) {
  __shared__ double part[4][64];
  const int t64 = threadIdx.x & 63, chunk = threadIdx.x >> 6;
  const int n = blockIdx.x * 64 + t64;
  const int b = n >> 10, hw = n & 1023;
  const float* zp = z + (size_t)b * CHW + hw;
  const int row = n & 127, tile = n >> 7;
  char* dst = (char*)Abf + (size_t)tile * 65536 + (size_t)chunk * 16384;
  const int rowoff = row * 128, sw = (row & 7) << 4;
  float* ztp = zt + (size_t)n * 256 + chunk * 64;
  double s = 0.0;
  #pragma unroll
  for (int kb = 0; kb < 8; ++kb) {
    us8 v;
    float tmp[8];
    #pragma unroll
    for (int j = 0; j < 8; ++j) {
      const int d = chunk * 64 + kb * 8 + j;
      const float f = zp[(size_t)d * HWD];
      tmp[j] = f;
      v[j] = f2bf(f);
      s += (double)f * (double)f;                 // d ascending
    }
    *(us8*)(dst + ((rowoff + kb * 16) ^ sw)) = v;
    *(float4*)(ztp + kb * 8)     = *(float4*)&tmp[0];
    *(float4*)(ztp + kb * 8 + 4) = *(float4*)&tmp[4];
  }
  part[chunk][t64] = s;
  __syncthreads();
  if (threadIdx.x < 64)
    zz[n] = (float)(part[0][t64] + part[1][t64] + part[2][t64] + part[3][t64]);
}

// ---------------- prepB: emb -> bf16 code images + ee (coalesced via LDS transpose) ----------------
__global__ __launch_bounds__(256) void k_prepB(const float* __restrict__ emb,
                                               unsigned short* __restrict__ Bbf,
                                               float* __restrict__ ee) {
  __shared__ float rows[64][257];   // +1 pad: 2-way max, free
  __shared__ double part[4][64];
  const int tid = threadIdx.x;
  const int k0 = blockIdx.x * 64;
  for (int i = tid; i < 16384; i += 256)          // coalesced: lane = d
    rows[i >> 8][i & 255] = emb[(size_t)k0 * DDIM + i];
  __syncthreads();
  const int t64 = tid & 63, chunk = tid >> 6;
  const int code = k0 + t64;
  const int row = code & 127, tile = code >> 7;
  char* dst = (char*)Bbf + (size_t)tile * 65536 + (size_t)chunk * 16384;
  const int rowoff = row * 128, sw = (row & 7) << 4;
  double s = 0.0;
  #pragma unroll
  for (int kb = 0; kb < 8; ++kb) {
    us8 v;
    #pragma unroll
    for (int j = 0; j < 8; ++j) {
      const float f = rows[t64][chunk * 64 + kb * 8 + j];
      v[j] = f2bf(f);
      s += (double)f * (double)f;
    }
    *(us8*)(dst + ((rowoff + kb * 16) ^ sw)) = v;
  }
  part[chunk][t64] = s;
  __syncthreads();
  if (tid < 64)
    ee[code] = (float)(part[0][t64] + part[1][t64] + part[2][t64] + part[3][t64]);
}

// ---------------- phase-1: 256x256 GEMM-min, m201-style 4-phase interleave per K-chunk ----------------
// grid 4096 = 64 token-groups x 64 code-groups; 512 thr = 8 waves (2 code-halves x 4 token-qtrs).
// Wave: 128 codes x 64 tokens via 8x4 frags of mfma_f32_16x16x32_bf16 (A=codes: C row=code, col=token).
// K=256 in 4 chunks of 64. Per chunk, 4 phases x 16 MFMA:
//   P0 {read a[0..3],b[0..1] (12)}  P1 {read a[4..7] (8)}  P2 {read b[2..3] (4)}  P3 {STAGE kc+2 (8 gloads)}
// each phase: reads -> barrier -> lgkmcnt(0) -> setprio(1) 16xMFMA setprio(0) -> barrier.
// End of chunk: counted vmcnt(8) (never 0 until kc==2 tail) - T3+T4+T5.
__global__ __launch_bounds__(512, 2) void k_mdist(
    const unsigned short* __restrict__ tokimg, const unsigned short* __restrict__ codimg,
    _Float16* __restrict__ subt) {
  __shared__ __attribute__((aligned(16))) char lds[131072];   // 2 x (32KB A + 32KB B)
  const int raw = blockIdx.x;
  // XCD p owns code-groups p*8..p*8+7 (1MB, L2-fit); 8x8 (tg x cg) supertiles inside.
  const int p = raw & 7, local = raw >> 3;
  const int st = local >> 6, q = local & 63;
  const int cg = p * 8 + (q >> 3);        // 0..63: codes cg*256
  const int tg = st * 8 + (q & 7);        // 0..63: tokens tg*256
  const int tid = threadIdx.x;
  const int w = tid >> 6, lane = tid & 63;
  const int cm = w >> 2, tn = w & 3;      // code-half, token-quarter
  const int fr = lane & 15, fq = lane >> 4;

  const char* asrc = (const char*)codimg + (size_t)(2 * cg) * 65536;  // codes  (A)
  const char* bsrc = (const char*)tokimg + (size_t)(2 * tg) * 65536;  // tokens (B)

  int aoff[8][2], boff[4][2];
  #pragma unroll
  for (int m = 0; m < 8; ++m)
    #pragma unroll
    for (int ks = 0; ks < 2; ++ks) {
      const int c = cm * 128 + m * 16 + fr;
      const int rl = c & 127;
      aoff[m][ks] = (c >> 7) * 16384 + ((rl * 128 + (ks * 4 + fq) * 16) ^ ((rl & 7) << 4));
    }
  #pragma unroll
  for (int n = 0; n < 4; ++n)
    #pragma unroll
    for (int ks = 0; ks < 2; ++ks) {
      const int t = tn * 64 + n * 16 + fr;
      const int rl = t & 127;
      boff[n][ks] = 32768 + (t >> 7) * 16384 + ((rl * 128 + (ks * 4 + fq) * 16) ^ ((rl & 7) << 4));
    }

  f32x4 acc[8][4];
  #pragma unroll
  for (int m = 0; m < 8; ++m)
    #pragma unroll
    for (int n = 0; n < 4; ++n) acc[m][n] = (f32x4)0.0f;

  // stage one K-chunk (A 32KB + B 32KB) into buffer `buf`: 8 loads per thread
  #define STAGE(buf, kc)                                                              \
    {                                                                                 \
      char* dstb = lds + (buf) * 65536;                                               \
      _Pragma("unroll")                                                               \
      for (int r = 0; r < 4; ++r) {                                                   \
        const int u = r * 512 + w * 64 + lane;                                        \
        const int si = u >> 10, off = (u & 1023) * 16;                                \
        __builtin_amdgcn_global_load_lds(                                             \
          (const __attribute__((address_space(1))) void*)(asrc + (size_t)si * 65536 + (kc) * 16384 + off), \
          (__attribute__((address_space(3))) void*)(dstb + u * 16), 16, 0, 0);        \
      }                                                                               \
      _Pragma("unroll")                                                               \
      for (int r = 0; r < 4; ++r) {                                                   \
        const int u = r * 512 + w * 64 + lane;                                        \
        const int si = u >> 10, off = (u & 1023) * 16;                                \
        __builtin_amdgcn_global_load_lds(                                             \
          (const __attribute__((address_space(1))) void*)(bsrc + (size_t)si * 65536 + (kc) * 16384 + off), \
          (__attribute__((address_space(3))) void*)(dstb + 32768 + u * 16), 16, 0, 0); \
      }                                                                               \
    }

  // phase sync: barrier, then wait own ds_reads, pin against MFMA hoist (rule #18)
  #define PHASE_SYNC()                                           \
    __builtin_amdgcn_sched_barrier(0);                           \
    __builtin_amdgcn_s_barrier();                                \
    asm volatile("s_waitcnt lgkmcnt(0)" ::: "memory");           \
    __builtin_amdgcn_sched_barrier(0);

  #define PHASE_END()                                            \
    __builtin_amdgcn_sched_barrier(0);                           \
    __builtin_amdgcn_s_barrier();

  // one C-quadrant x full K-chunk: 16 MFMA, setprio-bracketed (T5)
  #define MFMA_GROUP(M0, N0)                                                     \
    __builtin_amdgcn_s_setprio(1);                                               \
    _Pragma("unroll")                                                            \
    for (int ks = 0; ks < 2; ++ks)                                               \
      _Pragma("unroll")                                                          \
      for (int mm = 0; mm < 4; ++mm)                                             \
        _Pragma("unroll")                                                        \
        for (int nn = 0; nn < 2; ++nn)                                           \
          acc[(M0) + mm][(N0) + nn] = __builtin_amdgcn_mfma_f32_16x16x32_bf16(   \
              a[(M0) + mm][ks], b[(N0) + nn][ks], acc[(M0) + mm][(N0) + nn], 0, 0, 0); \
    __builtin_amdgcn_s_setprio(0);

  STAGE(0, 0);
  STAGE(1, 1);
  asm volatile("s_waitcnt vmcnt(8)" ::: "memory");   // oldest 8 (=buf0) landed
  __builtin_amdgcn_sched_barrier(0);
  __builtin_amdgcn_s_barrier();

  #pragma unroll
  for (int kc = 0; kc < 4; ++kc) {
    const char* bufb = lds + (kc & 1) * 65536;
    s8b a[8][2], b[4][2];
    // ---- P0: read a[0..3] + b[0..1] (12 b128); MFMA m0-3 x n0-1
    #pragma unroll
    for (int ks = 0; ks < 2; ++ks) {
      #pragma unroll
      for (int m = 0; m < 4; ++m) a[m][ks] = *(const s8b*)(bufb + aoff[m][ks]);
      #pragma unroll
      for (int n = 0; n < 2; ++n) b[n][ks] = *(const s8b*)(bufb + boff[n][ks]);
    }
    PHASE_SYNC();
    MFMA_GROUP(0, 0);
    PHASE_END();
    // ---- P1: read a[4..7] (8); MFMA m4-7 x n0-1
    #pragma unroll
    for (int ks = 0; ks < 2; ++ks)
      #pragma unroll
      for (int m = 4; m < 8; ++m) a[m][ks] = *(const s8b*)(bufb + aoff[m][ks]);
    PHASE_SYNC();
    MFMA_GROUP(4, 0);
    PHASE_END();
    // ---- P2: read b[2..3] (4); MFMA m0-3 x n2-3
    #pragma unroll
    for (int ks = 0; ks < 2; ++ks)
      #pragma unroll
      for (int n = 2; n < 4; ++n) b[n][ks] = *(const s8b*)(bufb + boff[n][ks]);
    PHASE_SYNC();
    MFMA_GROUP(0, 2);
    PHASE_END();
    // ---- P3: stage kc+2 into current (fully-read) buffer; MFMA m4-7 x n2-3
    if (kc < 2) STAGE(kc & 1, kc + 2);
    MFMA_GROUP(4, 2);
    if (kc < 2) {
      asm volatile("s_waitcnt vmcnt(8)" ::: "memory");   // next buffer's 8 landed; kc+2 in flight
    } else if (kc == 2) {
      asm volatile("s_waitcnt vmcnt(0)" ::: "memory");   // tail drain
    }
    PHASE_END();
  }

  // epilogue: per-token max per 32-code subtile (codes on reg+fq axis -> cheap).
  // outT aliases lds[0..4KB] (buf0): all buf0 reads fenced; all gload_lds drained at kc==2.
  _Float16* outT = (_Float16*)lds;          // [256 tokens][8 subtiles]
  #pragma unroll
  for (int s = 0; s < 4; ++s) {
    #pragma unroll
    for (int n = 0; n < 4; ++n) {
      float v = acc[2 * s][n][0];
      #pragma unroll
      for (int j = 1; j < 4; ++j) v = fmaxf(v, acc[2 * s][n][j]);
      #pragma unroll
      for (int j = 0; j < 4; ++j) v = fmaxf(v, acc[2 * s + 1][n][j]);
      v = fmaxf(v, __shfl_xor(v, 16, 64));  // fold fq bit0
      v = fmaxf(v, __shfl_xor(v, 32, 64));  // fold fq bit1 -> max over all 32 codes
      if (lane < 16)
        outT[(tn * 64 + n * 16 + fr) * 8 + cm * 4 + s] = (_Float16)(-2.0f * v);
    }
  }
  __syncthreads();
  if (tid < 256) {
    const int t = tid;                      // token n = tg*256 + t
    _Float16* g = subt + (size_t)(tg * 4 + (t >> 6)) * 32768 + (size_t)(t & 63) * 512 + cg * 8;
    *(h8*)g = *(const h8*)(outT + t * 8);
  }
}

// ---------------- phase-2: exact re-check of candidate subtiles, argmin (8 tokens/block) ----------------
__global__ __launch_bounds__(256) void k_pick(
    const float* __restrict__ zt, const float* __restrict__ emb,
    const float* __restrict__ zz, const float* __restrict__ ee,
    const _Float16* __restrict__ subt, int* __restrict__ idx,
    float* __restrict__ out_idxf) {
  __shared__ float zrow[256];
  __shared__ int clist[512];
  __shared__ int ccnt;
  __shared__ float wm[4];
  __shared__ unsigned long long bests[16];
  const int tid = threadIdx.x;
  const int w = tid >> 6, lane = tid & 63;
  const int g16 = lane >> 4, l16 = lane & 15;
  for (int ni = 0; ni < 8; ++ni) {
    const int n = blockIdx.x * 8 + ni;
    __syncthreads();                          // protect shared reuse across tokens
    if (tid == 0) ccnt = 0;
    zrow[tid] = zt[(size_t)n * 256 + tid];    // coalesced row
    const _Float16* tp = subt + (size_t)(n >> 6) * 32768 + (size_t)(n & 63) * 512;
    const float ta = (float)tp[tid];
    const float tb = (float)tp[tid + 256];
    float m2 = fminf(ta, tb);
    #pragma unroll
    for (int o = 32; o; o >>= 1) m2 = fminf(m2, __shfl_xor(m2, o, 64));
    if (lane == 0) wm[w] = m2;
    __syncthreads();
    const float thr = fminf(fminf(wm[0], wm[1]), fminf(wm[2], wm[3])) + MARGIN;
    if (ta <= thr) { int pp = atomicAdd(&ccnt, 1); clist[pp] = tid; }
    if (tb <= thr) { int pp = atomicAdd(&ccnt, 1); clist[pp] = tid + 256; }
    __syncthreads();
    const int nc = ccnt;
    const float zzn = zz[n];
    unsigned long long best = ~0ull;
    for (int ci = 0; ci < nc; ++ci) {
      const int t = clist[ci];               // candidate subtile (any order: min is total)
      #pragma unroll
      for (int pc = 0; pc < 2; ++pc) {
        const int k = t * 32 + w * 8 + pc * 4 + g16;   // 16 lanes per code
        const float* er = emb + (size_t)k * DDIM;
        double s = 0.0;
        #pragma unroll
        for (int qq = 0; qq < 4; ++qq) {
          const float4 ev = *(const float4*)(er + qq * 64 + l16 * 4);   // coalesced 256B
          const float4 zv = *(const float4*)(&zrow[qq * 64 + l16 * 4]);
          s += (double)zv.x * (double)ev.x + (double)zv.y * (double)ev.y
             + (double)zv.z * (double)ev.z + (double)zv.w * (double)ev.w;
        }
        #pragma unroll
        for (int o = 8; o; o >>= 1) s += __shfl_xor(s, o, 16);
        if (l16 == 0) {
          const float mm = (float)s;                   // exact dot -> one fp32 rounding
          const float d = (zzn + ee[k]) - 2.0f * mm;   // replicate ref quantization (d > 0)
          const unsigned long long c =
              ((unsigned long long)__float_as_uint(d) << 32) | (unsigned int)k;
          if (c < best) best = c;                      // lexicographic (d, k)
        }
      }
    }
    if (l16 == 0) bests[w * 4 + g16] = best;
    __syncthreads();
    if (tid == 0) {
      unsigned long long bb = bests[0];
      #pragma unroll
      for (int i = 1; i < 16; ++i) bb = bests[i] < bb ? bests[i] : bb;
      const int k0 = (int)(bb & 0xffffffffu);
      idx[n] = k0;
      out_idxf[n] = (float)k0;
    }
  }
}

// ---------------- scatter z_q (coalesced), loss partial, counts ----------------
__global__ __launch_bounds__(256) void k_scatter(
    const float* __restrict__ z, const float* __restrict__ emb,
    const int* __restrict__ idx, float* __restrict__ out_zq,
    int* __restrict__ counts, double* __restrict__ sums) {
  __shared__ float et[64][257];   // 64 tokens x 256 dims, pad 257
  __shared__ int sidx[64];
  __shared__ double w4[4];
  const int tg = blockIdx.x;      // 256 groups of 64 tokens
  const int n0 = tg * 64;
  const int b = n0 >> 10, hw0 = n0 & 1023;
  const int tid = threadIdx.x;
  if (tid < 64) sidx[tid] = idx[n0 + tid];
  __syncthreads();
  for (int i = tid; i < 16384; i += 256) {      // gather code rows (coalesced along d)
    const int t = i >> 8, d = i & 255;
    et[t][d] = emb[(size_t)sidx[t] * DDIM + d];
  }
  __syncthreads();
  const float* zb = z + (size_t)b * CHW + hw0;
  float* ob = out_zq + (size_t)b * CHW + hw0;
  double s = 0.0;
  for (int i = tid; i < 16384; i += 256) {      // NCHW order: coalesced z reads + zq writes
    const int d = i >> 6, t = i & 63;
    const float v = et[t][d];
    const float diff = v - zb[(size_t)d * HWD + t];
    ob[(size_t)d * HWD + t] = v;                // z_q_st == z_q numerically
    s += (double)diff * (double)diff;
  }
  #pragma unroll
  for (int o = 32; o; o >>= 1) s += __shfl_xor(s, o, 64);
  const int wd = tid >> 6, lane = tid & 63;
  if (lane == 0) w4[wd] = s;
  __syncthreads();
  if (tid == 0) atomicAdd(&sums[0], w4[0] + w4[1] + w4[2] + w4[3]);
  if (tid < 64) atomicAdd(&counts[sidx[tid]], 1);
}

// ---------------- entropy partial from counts ----------------
__global__ __launch_bounds__(256) void k_hist(const int* __restrict__ counts,
                                              double* __restrict__ sums) {
  const int i = blockIdx.x * 256 + threadIdx.x;
  const float em = (float)counts[i] * (1.0f / 16384.0f);
  const float term = em * logf(em + 1e-10f);
  double s = (double)term;
  #pragma unroll
  for (int o = 32; o; o >>= 1) s += __shfl_xor(s, o, 64);
  __shared__ double w4[4];
  const int wid = threadIdx.x >> 6, lane = threadIdx.x & 63;
  if (lane == 0) w4[wid] = s;
  __syncthreads();
  if (threadIdx.x == 0) atomicAdd(&sums[1], w4[0] + w4[1] + w4[2] + w4[3]);
}

// ---------------- finals ----------------
__global__ void k_final(const double* __restrict__ sums,
                        float* __restrict__ out_loss,
                        float* __restrict__ out_perp) {
  if (threadIdx.x == 0) {
    out_loss[0] = (float)(1.25 * sums[0] / 4194304.0);  // (1+BETA)*mean
    out_perp[0] = (float)exp(-sums[1]);
  }
}

extern "C" void kernel_launch(void* const* d_in, const int* in_sizes, int n_in,
                              void* d_out, int out_size, void* d_ws, size_t ws_size,
                              hipStream_t stream) {
  const float* z   = (const float*)d_in[0];   // [16,256,32,32]
  const float* emb = (const float*)d_in[1];   // [16384,256]
  float* out      = (float*)d_out;
  float* out_zq   = out;                      // 4194304
  float* out_loss = out + 4194304;
  float* out_perp = out + 4194305;
  float* out_idxf = out + 4194306;            // 16384 (idx as float)
  float* zt       = out;                      // [n][d] fp32 transpose; dead before k_scatter overwrites

  char* ws = (char*)d_ws;
  unsigned short* Abf = (unsigned short*)(ws + WS_ABF);
  unsigned short* Bbf = (unsigned short*)(ws + WS_BBF);
  _Float16* subt  = (_Float16*)(ws + WS_SUBT);
  float*  ee      = (float*)(ws + WS_EE);
  float*  zz      = (float*)(ws + WS_ZZ);
  int*    idx     = (int*)  (ws + WS_IDX);
  int*    counts  = (int*)  (ws + WS_CNT);
  double* sums    = (double*)(ws + WS_SUM);

  hipMemsetAsync(counts, 0, 65536 + 16, stream);

  k_prepA<<<256, 256, 0, stream>>>(z, Abf, zz, zt);
  k_prepB<<<256, 256, 0, stream>>>(emb, Bbf, ee);
  k_mdist<<<4096, 512, 0, stream>>>(Abf, Bbf, subt);
  k_pick <<<2048, 256, 0, stream>>>(zt, emb, zz, ee, subt, idx, out_idxf);
  k_scatter<<<256, 256, 0, stream>>>(z, emb, idx, out_zq, counts, sums);
  k_hist <<<64, 256, 0, stream>>>(counts, sums);
  k_final<<<1, 64, 0, stream>>>(sums, out_loss, out_perp);
}

// Round 7
// 335.336 us; speedup vs baseline: 1.0324x; 1.0204x over previous
//
#include <hip/hip_runtime.h>
#include <math.h>

#define NTOK   16384
#define DDIM   256
#define HWD    1024        // H*W per batch image
#define CHW    262144      // 256*1024 floats per batch
#define MARGIN 3.0e-4f     // i8 quant (8 sigma, two-sided) + ref d-grid + ee span + fp16
#define CLIPF  5.5f
#define QS     (127.0f/5.5f)
#define EQS    2080768.0f  // 16384*127: emb quantizes EXACTLY (|e|<=1/16384 -> |eq|<=127)
#define SCALE  (5.5f/(127.0f*127.0f*16384.0f))   // sz*se

// ws layout (bytes)
#define WS_TI8   0u          // 4 MB  i8 token images [128 tiles][4 chunks][128 rows][64B swz]
#define WS_CI8   4194304u    // 4 MB  i8 code  images
#define WS_SUBT  8388608u    // 16 MB fp16 subtile mins: [n>>6][n&63][512 subtiles]
#define WS_EE    25165824u   // 64KB
#define WS_ZZ    25231360u   // 64KB
#define WS_IDX   25296896u   // 64KB
#define WS_CNT   25362432u   // 64KB
#define WS_SUM   25427968u   // 16B (contiguous after counts)
#define WS_FLG   25428000u   // 16KB per-token clip flags

typedef __attribute__((ext_vector_type(4)))  int   i32x4;
typedef __attribute__((ext_vector_type(16))) char  c16;
typedef __attribute__((ext_vector_type(4)))  _Float16 h4;

// ---------------- fused prep: blocks 0..255 tokens, 256..511 codes ----------------
// image layout per 128-entity tile: [chunk 0..3][row 0..127][64B], byte-slot swizzle
// slot^=((row>>1)&3)  (16B slots). zt[n][d] fp32 + zz + clip flags (tokens); ee (codes).
__global__ __launch_bounds__(256) void k_prep(const float* __restrict__ z,
                                              const float* __restrict__ emb,
                                              char* __restrict__ Ti8,
                                              char* __restrict__ Ci8,
                                              float* __restrict__ zz,
                                              float* __restrict__ ee,
                                              float* __restrict__ zt,
                                              unsigned char* __restrict__ flags) {
  const int bid = blockIdx.x;
  const int tid = threadIdx.x;
  const int t64 = tid & 63, chunk = tid >> 6;
  if (bid < 256) {                      // ---- token role
    __shared__ double part[4][64];
    __shared__ int   fpart[4][64];
    const int n = bid * 64 + t64;
    const int b = n >> 10, hw = n & 1023;
    const float* zp = z + (size_t)b * CHW + hw;
    float tmp[64];
    double s = 0.0;
    int clip = 0;
    #pragma unroll
    for (int j = 0; j < 64; ++j) {      // coalesced across t64 for each j
      const float f = zp[(size_t)(chunk * 64 + j) * HWD];
      tmp[j] = f;
      s += (double)f * (double)f;
      clip |= (fabsf(f) > CLIPF) ? 1 : 0;
    }
    c16 q[4];
    #pragma unroll
    for (int sl = 0; sl < 4; ++sl)
      #pragma unroll
      for (int j = 0; j < 16; ++j)
        q[sl][j] = (char)(int)rintf(fminf(fmaxf(tmp[sl * 16 + j], -CLIPF), CLIPF) * QS);
    const int rl = n & 127, tile = n >> 7;
    char* dst = Ti8 + (size_t)tile * 32768 + chunk * 8192 + rl * 64;
    const int sw = ((rl >> 1) & 3) << 4;
    #pragma unroll
    for (int sl = 0; sl < 4; ++sl) *(c16*)(dst + ((sl * 16) ^ sw)) = q[sl];
    float* ztp = zt + (size_t)n * 256 + chunk * 64;
    #pragma unroll
    for (int j4 = 0; j4 < 16; ++j4) *(float4*)(ztp + j4 * 4) = *(float4*)&tmp[j4 * 4];
    part[chunk][t64] = s;
    fpart[chunk][t64] = clip;
    __syncthreads();
    if (tid < 64) {
      zz[n] = (float)(part[0][t64] + part[1][t64] + part[2][t64] + part[3][t64]);
      flags[n] = (unsigned char)(fpart[0][t64] | fpart[1][t64] | fpart[2][t64] | fpart[3][t64]);
    }
  } else {                              // ---- code role (coalesced via LDS transpose)
    __shared__ float rows[64][257];     // +1 pad
    __shared__ double part2[4][64];
    const int k0 = (bid - 256) * 64;
    for (int i = tid; i < 16384; i += 256)
      rows[i >> 8][i & 255] = emb[(size_t)k0 * DDIM + i];
    __syncthreads();
    const int code = k0 + t64;
    double s = 0.0;
    c16 q[4];
    #pragma unroll
    for (int sl = 0; sl < 4; ++sl)
      #pragma unroll
      for (int j = 0; j < 16; ++j) {
        const float f = rows[t64][chunk * 64 + sl * 16 + j];
        q[sl][j] = (char)(int)rintf(f * EQS);   // exact range, no clip possible
        s += (double)f * (double)f;
      }
    const int rl = code & 127, tile = code >> 7;
    char* dst = Ci8 + (size_t)tile * 32768 + chunk * 8192 + rl * 64;
    const int sw = ((rl >> 1) & 3) << 4;
    #pragma unroll
    for (int sl = 0; sl < 4; ++sl) *(c16*)(dst + ((sl * 16) ^ sw)) = q[sl];
    part2[chunk][t64] = s;
    __syncthreads();
    if (tid < 64)
      ee[code] = (float)(part2[0][t64] + part2[1][t64] + part2[2][t64] + part2[3][t64]);
  }
}

// ---------------- phase-1: i8 single-shot 128x128 GEMM-max per block ----------------
// grid 16384 = 128 code-tiles x 128 token-tiles; 256 thr = 4 waves (2 code x 2 token).
// Full K=256 staged once (A 32KB codes + B 32KB tokens = 64KB -> 2 blocks/CU), then
// 4 K-instrs of mfma_i32_16x16x64_i8 per frag with ZERO mid-loop barriers.
// A=codes -> C row=code, col=token (dtype-independent C layout, m121/m127).
__global__ __launch_bounds__(256) void k_mdist(
    const char* __restrict__ tokimg, const char* __restrict__ codimg,
    _Float16* __restrict__ subt) {
  __shared__ __attribute__((aligned(16))) char lds[65536];
  const int raw = blockIdx.x;
  // XCD p owns ctile p*16..p*16+15 (512KB code set, L2-fit); within: ttile-major reuse.
  const int p = raw & 7, local = raw >> 3;
  const int ctile = p * 16 + (local & 15);
  const int ttile = local >> 4;
  const int tid = threadIdx.x;
  const int w = tid >> 6, lane = tid & 63;
  const int wr = w >> 1, wc = w & 1;      // code-half, token-half (wave = 64x64)
  const int fr = lane & 15, fq = lane >> 4;
  const char* asrc = codimg + (size_t)ctile * 32768;
  const char* bsrc = tokimg + (size_t)ttile * 32768;

  // single-shot stage: 64KB, 16 loads/thread, linear (images pre-swizzled)
  #pragma unroll
  for (int r = 0; r < 8; ++r) {
    const int u = r * 256 + tid;
    __builtin_amdgcn_global_load_lds(
        (const __attribute__((address_space(1))) void*)(asrc + u * 16),
        (__attribute__((address_space(3))) void*)(lds + u * 16), 16, 0, 0);
  }
  #pragma unroll
  for (int r = 0; r < 8; ++r) {
    const int u = r * 256 + tid;
    __builtin_amdgcn_global_load_lds(
        (const __attribute__((address_space(1))) void*)(bsrc + u * 16),
        (__attribute__((address_space(3))) void*)(lds + 32768 + u * 16), 16, 0, 0);
  }

  int aoff[4][4], boff[4][4];             // [frag][kc]
  #pragma unroll
  for (int m = 0; m < 4; ++m)
    #pragma unroll
    for (int kc = 0; kc < 4; ++kc) {
      const int c = wr * 64 + m * 16 + fr;
      aoff[m][kc] = kc * 8192 + c * 64 + ((fq * 16) ^ (((c >> 1) & 3) << 4));
      const int t = wc * 64 + m * 16 + fr;
      boff[m][kc] = 32768 + kc * 8192 + t * 64 + ((fq * 16) ^ (((t >> 1) & 3) << 4));
    }

  i32x4 acc[4][4];
  #pragma unroll
  for (int m = 0; m < 4; ++m)
    #pragma unroll
    for (int n = 0; n < 4; ++n) acc[m][n] = (i32x4)0;

  __syncthreads();                        // drains vmcnt(0): stage visible

  #pragma unroll
  for (int kc = 0; kc < 4; ++kc) {        // K=256 in 4 x K=64 instrs, no barriers
    i32x4 a[4], b[4];
    #pragma unroll
    for (int m = 0; m < 4; ++m) a[m] = *(const i32x4*)(lds + aoff[m][kc]);
    #pragma unroll
    for (int n = 0; n < 4; ++n) b[n] = *(const i32x4*)(lds + boff[n][kc]);
    #pragma unroll
    for (int m = 0; m < 4; ++m)
      #pragma unroll
      for (int n = 0; n < 4; ++n)
        acc[m][n] = __builtin_amdgcn_mfma_i32_16x16x64_i8(a[m], b[n], acc[m][n], 0, 0, 0);
  }

  // reduce: integer max per (32-code subtile u, token frag n); codes on reg+fq axis
  float red[2][4];
  #pragma unroll
  for (int u = 0; u < 2; ++u)
    #pragma unroll
    for (int n = 0; n < 4; ++n) {
      int v = acc[2 * u][n][0];
      #pragma unroll
      for (int j = 1; j < 4; ++j) v = max(v, acc[2 * u][n][j]);
      #pragma unroll
      for (int j = 0; j < 4; ++j) v = max(v, acc[2 * u + 1][n][j]);
      v = max(v, __shfl_xor(v, 16, 64));
      v = max(v, __shfl_xor(v, 32, 64));  // max over all 32 codes of the subtile
      red[u][n] = -2.0f * SCALE * (float)v;
    }
  __syncthreads();                        // all LDS frag reads done -> safe to alias
  _Float16* outT = (_Float16*)lds;        // [128 tokens][4 subtiles]
  if (lane < 16) {
    #pragma unroll
    for (int u = 0; u < 2; ++u)
      #pragma unroll
      for (int n = 0; n < 4; ++n)
        outT[(wc * 64 + n * 16 + fr) * 4 + wr * 2 + u] = (_Float16)red[u][n];
  }
  __syncthreads();
  if (tid < 128) {
    const int tok = ttile * 128 + tid;
    *(h4*)(subt + (size_t)(tok >> 6) * 32768 + (size_t)(tok & 63) * 512 + ctile * 4) =
        *(const h4*)(outT + tid * 4);
  }
}

// ---------------- phase-2: exact re-check of candidate subtiles, argmin (8 tokens/block) ----------------
__global__ __launch_bounds__(256) void k_pick(
    const float* __restrict__ zt, const float* __restrict__ emb,
    const float* __restrict__ zz, const float* __restrict__ ee,
    const _Float16* __restrict__ subt, const unsigned char* __restrict__ flags,
    int* __restrict__ idx, float* __restrict__ out_idxf) {
  __shared__ float zrow[256];
  __shared__ int clist[512];
  __shared__ int ccnt;
  __shared__ float wm[4];
  __shared__ unsigned long long bests[16];
  const int tid = threadIdx.x;
  const int w = tid >> 6, lane = tid & 63;
  const int g16 = lane >> 4, l16 = lane & 15;
  for (int ni = 0; ni < 8; ++ni) {
    const int n = blockIdx.x * 8 + ni;
    __syncthreads();                          // protect shared reuse across tokens
    if (tid == 0) ccnt = 0;
    zrow[tid] = zt[(size_t)n * 256 + tid];    // coalesced row
    const _Float16* tp = subt + (size_t)(n >> 6) * 32768 + (size_t)(n & 63) * 512;
    const float ta = (float)tp[tid];
    const float tb = (float)tp[tid + 256];
    float m2 = fminf(ta, tb);
    #pragma unroll
    for (int o = 32; o; o >>= 1) m2 = fminf(m2, __shfl_xor(m2, o, 64));
    if (lane == 0) wm[w] = m2;
    __syncthreads();
    // clipped token -> exhaustive exact recheck (flags expected all-zero)
    const float thr = flags[n] ? 3.0e38f
                               : fminf(fminf(wm[0], wm[1]), fminf(wm[2], wm[3])) + MARGIN;
    if (ta <= thr) { int pp = atomicAdd(&ccnt, 1); clist[pp] = tid; }
    if (tb <= thr) { int pp = atomicAdd(&ccnt, 1); clist[pp] = tid + 256; }
    __syncthreads();
    const int nc = ccnt;
    const float zzn = zz[n];
    unsigned long long best = ~0ull;
    for (int ci = 0; ci < nc; ++ci) {
      const int t = clist[ci];               // candidate subtile (any order: min is total)
      #pragma unroll
      for (int pc = 0; pc < 2; ++pc) {
        const int k = t * 32 + w * 8 + pc * 4 + g16;   // 16 lanes per code
        const float* er = emb + (size_t)k * DDIM;
        double s = 0.0;
        #pragma unroll
        for (int qq = 0; qq < 4; ++qq) {
          const float4 ev = *(const float4*)(er + qq * 64 + l16 * 4);   // coalesced 256B
          const float4 zv = *(const float4*)(&zrow[qq * 64 + l16 * 4]);
          s += (double)zv.x * (double)ev.x + (double)zv.y * (double)ev.y
             + (double)zv.z * (double)ev.z + (double)zv.w * (double)ev.w;
        }
        #pragma unroll
        for (int o = 8; o; o >>= 1) s += __shfl_xor(s, o, 16);
        if (l16 == 0) {
          const float mm = (float)s;                   // exact dot -> one fp32 rounding
          const float d = (zzn + ee[k]) - 2.0f * mm;   // replicate ref quantization (d > 0)
          const unsigned long long c =
              ((unsigned long long)__float_as_uint(d) << 32) | (unsigned int)k;
          if (c < best) best = c;                      // lexicographic (d, k)
        }
      }
    }
    if (l16 == 0) bests[w * 4 + g16] = best;
    __syncthreads();
    if (tid == 0) {
      unsigned long long bb = bests[0];
      #pragma unroll
      for (int i = 1; i < 16; ++i) bb = bests[i] < bb ? bests[i] : bb;
      const int k0 = (int)(bb & 0xffffffffu);
      idx[n] = k0;
      out_idxf[n] = (float)k0;
    }
  }
}

// ---------------- scatter z_q (coalesced), loss partial, counts ----------------
__global__ __launch_bounds__(256) void k_scatter(
    const float* __restrict__ z, const float* __restrict__ emb,
    const int* __restrict__ idx, float* __restrict__ out_zq,
    int* __restrict__ counts, double* __restrict__ sums) {
  __shared__ float et[64][257];   // 64 tokens x 256 dims, pad 257
  __shared__ int sidx[64];
  __shared__ double w4[4];
  const int tg = blockIdx.x;      // 256 groups of 64 tokens
  const int n0 = tg * 64;
  const int b = n0 >> 10, hw0 = n0 & 1023;
  const int tid = threadIdx.x;
  if (tid < 64) sidx[tid] = idx[n0 + tid];
  __syncthreads();
  for (int i = tid; i < 16384; i += 256) {      // gather code rows (coalesced along d)
    const int t = i >> 8, d = i & 255;
    et[t][d] = emb[(size_t)sidx[t] * DDIM + d];
  }
  __syncthreads();
  const float* zb = z + (size_t)b * CHW + hw0;
  float* ob = out_zq + (size_t)b * CHW + hw0;
  double s = 0.0;
  for (int i = tid; i < 16384; i += 256) {      // NCHW order: coalesced z reads + zq writes
    const int d = i >> 6, t = i & 63;
    const float v = et[t][d];
    const float diff = v - zb[(size_t)d * HWD + t];
    ob[(size_t)d * HWD + t] = v;                // z_q_st == z_q numerically
    s += (double)diff * (double)diff;
  }
  #pragma unroll
  for (int o = 32; o; o >>= 1) s += __shfl_xor(s, o, 64);
  const int wd = tid >> 6, lane = tid & 63;
  if (lane == 0) w4[wd] = s;
  __syncthreads();
  if (tid == 0) atomicAdd(&sums[0], w4[0] + w4[1] + w4[2] + w4[3]);
  if (tid < 64) atomicAdd(&counts[sidx[tid]], 1);
}

// ---------------- entropy partial from counts ----------------
__global__ __launch_bounds__(256) void k_hist(const int* __restrict__ counts,
                                              double* __restrict__ sums) {
  const int i = blockIdx.x * 256 + threadIdx.x;
  const float em = (float)counts[i] * (1.0f / 16384.0f);
  const float term = em * logf(em + 1e-10f);
  double s = (double)term;
  #pragma unroll
  for (int o = 32; o; o >>= 1) s += __shfl_xor(s, o, 64);
  __shared__ double w4[4];
  const int wid = threadIdx.x >> 6, lane = threadIdx.x & 63;
  if (lane == 0) w4[wid] = s;
  __syncthreads();
  if (threadIdx.x == 0) atomicAdd(&sums[1], w4[0] + w4[1] + w4[2] + w4[3]);
}

// ---------------- finals ----------------
__global__ void k_final(const double* __restrict__ sums,
                        float* __restrict__ out_loss,
                        float* __restrict__ out_perp) {
  if (threadIdx.x == 0) {
    out_loss[0] = (float)(1.25 * sums[0] / 4194304.0);  // (1+BETA)*mean
    out_perp[0] = (float)exp(-sums[1]);
  }
}

extern "C" void kernel_launch(void* const* d_in, const int* in_sizes, int n_in,
                              void* d_out, int out_size, void* d_ws, size_t ws_size,
                              hipStream_t stream) {
  const float* z   = (const float*)d_in[0];   // [16,256,32,32]
  const float* emb = (const float*)d_in[1];   // [16384,256]
  float* out      = (float*)d_out;
  float* out_zq   = out;                      // 4194304
  float* out_loss = out + 4194304;
  float* out_perp = out + 4194305;
  float* out_idxf = out + 4194306;            // 16384 (idx as float)
  float* zt       = out;                      // [n][d] fp32; exactly zq-sized, dead before k_scatter

  char* ws = (char*)d_ws;
  char* Ti8 = ws + WS_TI8;
  char* Ci8 = ws + WS_CI8;
  _Float16* subt  = (_Float16*)(ws + WS_SUBT);
  float*  ee      = (float*)(ws + WS_EE);
  float*  zz      = (float*)(ws + WS_ZZ);
  int*    idx     = (int*)  (ws + WS_IDX);
  int*    counts  = (int*)  (ws + WS_CNT);
  double* sums    = (double*)(ws + WS_SUM);
  unsigned char* flags = (unsigned char*)(ws + WS_FLG);

  hipMemsetAsync(counts, 0, 65536 + 16, stream);

  k_prep <<<512, 256, 0, stream>>>(z, emb, Ti8, Ci8, zz, ee, zt, flags);
  k_mdist<<<16384, 256, 0, stream>>>(Ti8, Ci8, subt);
  k_pick <<<2048, 256, 0, stream>>>(zt, emb, zz, ee, subt, flags, idx, out_idxf);
  k_scatter<<<256, 256, 0, stream>>>(z, emb, idx, out_zq, counts, sums);
  k_hist <<<64, 256, 0, stream>>>(counts, sums);
  k_final<<<1, 64, 0, stream>>>(sums, out_loss, out_perp);
}

// Round 8
// 221.853 us; speedup vs baseline: 1.5605x; 1.5115x over previous
//
#include <hip/hip_runtime.h>
#include <math.h>

#define NTOK   16384
#define DDIM   256
#define HWD    1024        // H*W per batch image
#define CHW    262144      // 256*1024 floats per batch
#define MARGIN 3.0e-4f     // i8 stat (8 sigma of est-diff) + ref d-grid + fp16 quant
#define CLIPF  5.5f
#define QS     (127.0f/5.5f)
#define EQS    2080768.0f  // 16384*127
#define SCALE  (5.5f/(127.0f*127.0f*16384.0f))   // sz*se

// ws layout (bytes)
#define WS_TI8   0u          // 4 MB  i8 token images [128 tiles][4 chunks][128 rows][64B swz]
#define WS_CI8   4194304u    // 4 MB  i8 code  images
#define WS_M1    8388608u    // 8 MB  fp16 min1: [n][256 subtiles]
#define WS_M2    16777216u   // 8 MB  fp16 min2: [256 subtiles][n]
#define WS_ARG   25165824u   // 4 MB  u8 argmin-in-subtile: [256 subtiles][n]
#define WS_FLG   29360128u   // 16KB per-token clip flags
#define WS_EE    29376512u   // 64KB
#define WS_ZZ    29442048u   // 64KB
#define WS_IDX   29507584u   // 64KB
#define WS_CNT   29573120u   // 64KB
#define WS_SUM   29638656u   // 16B (contiguous after counts)

typedef __attribute__((ext_vector_type(4)))  int   i32x4;
typedef __attribute__((ext_vector_type(16))) char  c16;

// ---------------- fused prep: blocks 0..255 tokens, 256..511 codes ----------------
__global__ __launch_bounds__(256) void k_prep(const float* __restrict__ z,
                                              const float* __restrict__ emb,
                                              char* __restrict__ Ti8,
                                              char* __restrict__ Ci8,
                                              float* __restrict__ zz,
                                              float* __restrict__ ee,
                                              float* __restrict__ zt,
                                              unsigned char* __restrict__ flags) {
  const int bid = blockIdx.x;
  const int tid = threadIdx.x;
  const int t64 = tid & 63, chunk = tid >> 6;
  if (bid < 256) {                      // ---- token role
    __shared__ double part[4][64];
    __shared__ int   fpart[4][64];
    const int n = bid * 64 + t64;
    const int b = n >> 10, hw = n & 1023;
    const float* zp = z + (size_t)b * CHW + hw;
    float tmp[64];
    double s = 0.0;
    int clip = 0;
    #pragma unroll
    for (int j = 0; j < 64; ++j) {      // coalesced across t64 for each j
      const float f = zp[(size_t)(chunk * 64 + j) * HWD];
      tmp[j] = f;
      s += (double)f * (double)f;
      clip |= (fabsf(f) > CLIPF) ? 1 : 0;
    }
    c16 q[4];
    #pragma unroll
    for (int sl = 0; sl < 4; ++sl)
      #pragma unroll
      for (int j = 0; j < 16; ++j)
        q[sl][j] = (char)(int)rintf(fminf(fmaxf(tmp[sl * 16 + j], -CLIPF), CLIPF) * QS);
    const int rl = n & 127, tile = n >> 7;
    char* dst = Ti8 + (size_t)tile * 32768 + chunk * 8192 + rl * 64;
    const int sw = ((rl >> 1) & 3) << 4;
    #pragma unroll
    for (int sl = 0; sl < 4; ++sl) *(c16*)(dst + ((sl * 16) ^ sw)) = q[sl];
    float* ztp = zt + (size_t)n * 256 + chunk * 64;
    #pragma unroll
    for (int j4 = 0; j4 < 16; ++j4) *(float4*)(ztp + j4 * 4) = *(float4*)&tmp[j4 * 4];
    part[chunk][t64] = s;
    fpart[chunk][t64] = clip;
    __syncthreads();
    if (tid < 64) {
      zz[n] = (float)(part[0][t64] + part[1][t64] + part[2][t64] + part[3][t64]);
      flags[n] = (unsigned char)(fpart[0][t64] | fpart[1][t64] | fpart[2][t64] | fpart[3][t64]);
    }
  } else {                              // ---- code role (coalesced via LDS transpose)
    __shared__ float rows[64][257];     // +1 pad
    __shared__ double part2[4][64];
    const int k0 = (bid - 256) * 64;
    for (int i = tid; i < 16384; i += 256)
      rows[i >> 8][i & 255] = emb[(size_t)k0 * DDIM + i];
    __syncthreads();
    const int code = k0 + t64;
    double s = 0.0;
    c16 q[4];
    #pragma unroll
    for (int sl = 0; sl < 4; ++sl)
      #pragma unroll
      for (int j = 0; j < 16; ++j) {
        const float f = rows[t64][chunk * 64 + sl * 16 + j];
        q[sl][j] = (char)(int)rintf(f * EQS);   // range-safe (|e|<=1/16384 -> |q|<=127)
        s += (double)f * (double)f;
      }
    const int rl = code & 127, tile = code >> 7;
    char* dst = Ci8 + (size_t)tile * 32768 + chunk * 8192 + rl * 64;
    const int sw = ((rl >> 1) & 3) << 4;
    #pragma unroll
    for (int sl = 0; sl < 4; ++sl) *(c16*)(dst + ((sl * 16) ^ sw)) = q[sl];
    part2[chunk][t64] = s;
    __syncthreads();
    if (tid < 64)
      ee[code] = (float)(part2[0][t64] + part2[1][t64] + part2[2][t64] + part2[3][t64]);
  }
}

// ---------------- phase-1: i8 single-shot 128x128 GEMM, (min1,arg,min2) per 64-code subtile ----------------
// grid 16384 = 128 code-tiles x 128 token-tiles; 256 thr = 4 waves (2 code x 2 token).
// Full K=256 staged once (64KB LDS -> 2 blocks/CU). A=codes: C row=code, col=token.
// Subtile = (ctile, wr): 64 codes; global subtile id t = ctile*2+wr, code k = t*64 + arg6.
__global__ __launch_bounds__(256) void k_mdist(
    const char* __restrict__ tokimg, const char* __restrict__ codimg,
    _Float16* __restrict__ M1, _Float16* __restrict__ M2,
    unsigned char* __restrict__ ARG) {
  __shared__ __attribute__((aligned(16))) char lds[65536];
  const int raw = blockIdx.x;
  // XCD p owns ctile p*16..p*16+15 (512KB code set, L2-fit); within: ttile-major reuse.
  const int p = raw & 7, local = raw >> 3;
  const int ctile = p * 16 + (local & 15);
  const int ttile = local >> 4;
  const int tid = threadIdx.x;
  const int w = tid >> 6, lane = tid & 63;
  const int wr = w >> 1, wc = w & 1;      // code-half, token-half (wave = 64x64)
  const int fr = lane & 15, fq = lane >> 4;
  const char* asrc = codimg + (size_t)ctile * 32768;
  const char* bsrc = tokimg + (size_t)ttile * 32768;

  // single-shot stage: 64KB, 16 loads/thread, linear (images pre-swizzled)
  #pragma unroll
  for (int r = 0; r < 8; ++r) {
    const int u = r * 256 + tid;
    __builtin_amdgcn_global_load_lds(
        (const __attribute__((address_space(1))) void*)(asrc + u * 16),
        (__attribute__((address_space(3))) void*)(lds + u * 16), 16, 0, 0);
  }
  #pragma unroll
  for (int r = 0; r < 8; ++r) {
    const int u = r * 256 + tid;
    __builtin_amdgcn_global_load_lds(
        (const __attribute__((address_space(1))) void*)(bsrc + u * 16),
        (__attribute__((address_space(3))) void*)(lds + 32768 + u * 16), 16, 0, 0);
  }

  int aoff[4][4], boff[4][4];             // [frag][kc]
  #pragma unroll
  for (int m = 0; m < 4; ++m)
    #pragma unroll
    for (int kc = 0; kc < 4; ++kc) {
      const int c = wr * 64 + m * 16 + fr;
      aoff[m][kc] = kc * 8192 + c * 64 + ((fq * 16) ^ (((c >> 1) & 3) << 4));
      const int t = wc * 64 + m * 16 + fr;
      boff[m][kc] = 32768 + kc * 8192 + t * 64 + ((fq * 16) ^ (((t >> 1) & 3) << 4));
    }

  i32x4 acc[4][4];
  #pragma unroll
  for (int m = 0; m < 4; ++m)
    #pragma unroll
    for (int n = 0; n < 4; ++n) acc[m][n] = (i32x4)0;

  __syncthreads();                        // drains vmcnt(0): stage visible

  #pragma unroll
  for (int kc = 0; kc < 4; ++kc) {        // K=256 in 4 x K=64 instrs, no barriers
    i32x4 a[4], b[4];
    #pragma unroll
    for (int m = 0; m < 4; ++m) a[m] = *(const i32x4*)(lds + aoff[m][kc]);
    #pragma unroll
    for (int n = 0; n < 4; ++n) b[n] = *(const i32x4*)(lds + boff[n][kc]);
    #pragma unroll
    for (int m = 0; m < 4; ++m)
      #pragma unroll
      for (int n = 0; n < 4; ++n)
        acc[m][n] = __builtin_amdgcn_mfma_i32_16x16x64_i8(a[m], b[n], acc[m][n], 0, 0, 0);
  }

  // epilogue: per (token, wr-subtile) top-2 of v (=> min1/min2 of d_est) + argmax.
  // lane holds 16 values (m x j) for token col fr; fold fq via shfl 16,32.
  __syncthreads();                        // all LDS frag reads done -> safe to alias
  _Float16* m1l = (_Float16*)lds;                   // [128][2]
  _Float16* m2l = (_Float16*)(lds + 512);           // [128][2]
  unsigned char* agl = (unsigned char*)(lds + 1024);// [128][2]
  #pragma unroll
  for (int n = 0; n < 4; ++n) {
    int v1 = acc[0][n][0], a1 = fq * 4, v2 = (int)0x80000000;
    #pragma unroll
    for (int m = 0; m < 4; ++m)
      #pragma unroll
      for (int j = 0; j < 4; ++j) {
        if (m == 0 && j == 0) continue;
        const int v = acc[m][n][j];
        const int id = m * 16 + fq * 4 + j;
        if (v > v1) { v2 = v1; v1 = v; a1 = id; }
        else if (v > v2) v2 = v;
      }
    #pragma unroll
    for (int off = 16; off <= 32; off <<= 1) {
      const int o1 = __shfl_xor(v1, off, 64);
      const int oa = __shfl_xor(a1, off, 64);
      const int o2 = __shfl_xor(v2, off, 64);
      if (o1 > v1) { v2 = v1 > o2 ? v1 : o2; v1 = o1; a1 = oa; }
      else v2 = v2 > o2 ? v2 : o2;
    }
    if (lane < 16) {
      const int tl = wc * 64 + n * 16 + fr;
      m1l[tl * 2 + wr] = (_Float16)(-2.0f * SCALE * (float)v1);
      m2l[tl * 2 + wr] = (_Float16)(-2.0f * SCALE * (float)v2);
      agl[tl * 2 + wr] = (unsigned char)a1;
    }
  }
  __syncthreads();
  if (tid < 128) {
    const int tok = ttile * 128 + tid;
    *(unsigned int*)((char*)M1 + (size_t)tok * 512 + ctile * 4) =
        *(const unsigned int*)(m1l + tid * 2);
    M2[(size_t)(ctile * 2) * NTOK + tok]     = m2l[tid * 2];
    M2[(size_t)(ctile * 2 + 1) * NTOK + tok] = m2l[tid * 2 + 1];
    ARG[(size_t)(ctile * 2) * NTOK + tok]     = agl[tid * 2];
    ARG[(size_t)(ctile * 2 + 1) * NTOK + tok] = agl[tid * 2 + 1];
  }
}

// ---------------- phase-2: exact re-check of candidate CODES, argmin (8 tokens/block) ----------------
__global__ __launch_bounds__(256) void k_pick(
    const float* __restrict__ zt, const float* __restrict__ emb,
    const float* __restrict__ zz, const float* __restrict__ ee,
    const _Float16* __restrict__ M1, const _Float16* __restrict__ M2,
    const unsigned char* __restrict__ ARG, const unsigned char* __restrict__ flags,
    int* __restrict__ idx, float* __restrict__ out_idxf) {
  __shared__ float zrow[256];
  __shared__ int clist[2048];
  __shared__ int ccnt;
  __shared__ float wm[4];
  __shared__ unsigned long long bests[16];
  const int tid = threadIdx.x;
  const int w = tid >> 6, lane = tid & 63;
  const int g16 = lane >> 4, l16 = lane & 15;
  const int G = w * 4 + g16;              // 16 code-groups of 16 lanes
  for (int ni = 0; ni < 8; ++ni) {
    const int n = blockIdx.x * 8 + ni;
    __syncthreads();                      // protect shared reuse across tokens
    if (tid == 0) ccnt = 0;
    zrow[tid] = zt[(size_t)n * 256 + tid];
    const float ta = (float)M1[(size_t)n * 256 + tid];   // my subtile's min1
    float mr = ta;
    #pragma unroll
    for (int o = 32; o; o >>= 1) mr = fminf(mr, __shfl_xor(mr, o, 64));
    if (lane == 0) wm[w] = mr;
    __syncthreads();
    const int ex0 = flags[n];
    const float thr = ex0 ? 3.0e38f
                          : fminf(fminf(wm[0], wm[1]), fminf(wm[2], wm[3])) + MARGIN;
    if (!ex0 && ta <= thr) {              // candidate subtile tid
      const float m2v = (float)M2[(size_t)tid * NTOK + n];
      if (m2v > thr) {                    // only the argmin code can be in the window
        const int pos = atomicAdd(&ccnt, 1);
        if (pos < 2048) clist[pos] = tid * 64 + (int)ARG[(size_t)tid * NTOK + n];
      } else {                            // rare: 2+ codes in window -> whole subtile
        const int pos = atomicAdd(&ccnt, 64);
        if (pos + 64 <= 2048)
          for (int i = 0; i < 64; ++i) clist[pos + i] = tid * 64 + i;
      }
    }
    __syncthreads();
    const int doEx = ex0 || (ccnt > 2048);        // clip or overflow -> exhaustive
    const int nc = doEx ? 16384 : ccnt;
    const float zzn = zz[n];
    unsigned long long best = ~0ull;
    for (int ci = 0; ci < nc; ci += 16) {         // 16 codes in parallel
      int k;
      if (doEx) k = ci + G;
      else { const int sl = ci + G; k = clist[sl < nc ? sl : 0]; }  // dup harmless
      const float* er = emb + (size_t)k * DDIM;
      double s = 0.0;
      #pragma unroll
      for (int qq = 0; qq < 4; ++qq) {
        const float4 ev = *(const float4*)(er + qq * 64 + l16 * 4);   // coalesced 256B
        const float4 zv = *(const float4*)(&zrow[qq * 64 + l16 * 4]);
        s += (double)zv.x * (double)ev.x + (double)zv.y * (double)ev.y
           + (double)zv.z * (double)ev.z + (double)zv.w * (double)ev.w;
      }
      #pragma unroll
      for (int o = 8; o; o >>= 1) s += __shfl_xor(s, o, 16);
      if (l16 == 0) {
        const float mm = (float)s;                   // exact dot -> one fp32 rounding
        const float d = (zzn + ee[k]) - 2.0f * mm;   // replicate ref quantization (d > 0)
        const unsigned long long c =
            ((unsigned long long)__float_as_uint(d) << 32) | (unsigned int)k;
        if (c < best) best = c;                      // lexicographic (d, k)
      }
    }
    if (l16 == 0) bests[G] = best;
    __syncthreads();
    if (tid == 0) {
      unsigned long long bb = bests[0];
      #pragma unroll
      for (int i = 1; i < 16; ++i) bb = bests[i] < bb ? bests[i] : bb;
      const int k0 = (int)(bb & 0xffffffffu);
      idx[n] = k0;
      out_idxf[n] = (float)k0;
    }
  }
}

// ---------------- scatter z_q (coalesced), loss partial, counts ----------------
__global__ __launch_bounds__(256) void k_scatter(
    const float* __restrict__ z, const float* __restrict__ emb,
    const int* __restrict__ idx, float* __restrict__ out_zq,
    int* __restrict__ counts, double* __restrict__ sums) {
  __shared__ float et[64][257];   // 64 tokens x 256 dims, pad 257
  __shared__ int sidx[64];
  __shared__ double w4[4];
  const int tg = blockIdx.x;      // 256 groups of 64 tokens
  const int n0 = tg * 64;
  const int b = n0 >> 10, hw0 = n0 & 1023;
  const int tid = threadIdx.x;
  if (tid < 64) sidx[tid] = idx[n0 + tid];
  __syncthreads();
  for (int i = tid; i < 16384; i += 256) {      // gather code rows (coalesced along d)
    const int t = i >> 8, d = i & 255;
    et[t][d] = emb[(size_t)sidx[t] * DDIM + d];
  }
  __syncthreads();
  const float* zb = z + (size_t)b * CHW + hw0;
  float* ob = out_zq + (size_t)b * CHW + hw0;
  double s = 0.0;
  for (int i = tid; i < 16384; i += 256) {      // NCHW order: coalesced z reads + zq writes
    const int d = i >> 6, t = i & 63;
    const float v = et[t][d];
    const float diff = v - zb[(size_t)d * HWD + t];
    ob[(size_t)d * HWD + t] = v;                // z_q_st == z_q numerically
    s += (double)diff * (double)diff;
  }
  #pragma unroll
  for (int o = 32; o; o >>= 1) s += __shfl_xor(s, o, 64);
  const int wd = tid >> 6, lane = tid & 63;
  if (lane == 0) w4[wd] = s;
  __syncthreads();
  if (tid == 0) atomicAdd(&sums[0], w4[0] + w4[1] + w4[2] + w4[3]);
  if (tid < 64) atomicAdd(&counts[sidx[tid]], 1);
}

// ---------------- entropy partial from counts ----------------
__global__ __launch_bounds__(256) void k_hist(const int* __restrict__ counts,
                                              double* __restrict__ sums) {
  const int i = blockIdx.x * 256 + threadIdx.x;
  const float em = (float)counts[i] * (1.0f / 16384.0f);
  const float term = em * logf(em + 1e-10f);
  double s = (double)term;
  #pragma unroll
  for (int o = 32; o; o >>= 1) s += __shfl_xor(s, o, 64);
  __shared__ double w4[4];
  const int wid = threadIdx.x >> 6, lane = threadIdx.x & 63;
  if (lane == 0) w4[wid] = s;
  __syncthreads();
  if (threadIdx.x == 0) atomicAdd(&sums[1], w4[0] + w4[1] + w4[2] + w4[3]);
}

// ---------------- finals ----------------
__global__ void k_final(const double* __restrict__ sums,
                        float* __restrict__ out_loss,
                        float* __restrict__ out_perp) {
  if (threadIdx.x == 0) {
    out_loss[0] = (float)(1.25 * sums[0] / 4194304.0);  // (1+BETA)*mean
    out_perp[0] = (float)exp(-sums[1]);
  }
}

extern "C" void kernel_launch(void* const* d_in, const int* in_sizes, int n_in,
                              void* d_out, int out_size, void* d_ws, size_t ws_size,
                              hipStream_t stream) {
  const float* z   = (const float*)d_in[0];   // [16,256,32,32]
  const float* emb = (const float*)d_in[1];   // [16384,256]
  float* out      = (float*)d_out;
  float* out_zq   = out;                      // 4194304
  float* out_loss = out + 4194304;
  float* out_perp = out + 4194305;
  float* out_idxf = out + 4194306;            // 16384 (idx as float)
  float* zt       = out;                      // [n][d] fp32; dead before k_scatter overwrites

  char* ws = (char*)d_ws;
  char* Ti8 = ws + WS_TI8;
  char* Ci8 = ws + WS_CI8;
  _Float16* M1 = (_Float16*)(ws + WS_M1);
  _Float16* M2 = (_Float16*)(ws + WS_M2);
  unsigned char* ARG = (unsigned char*)(ws + WS_ARG);
  unsigned char* flags = (unsigned char*)(ws + WS_FLG);
  float*  ee      = (float*)(ws + WS_EE);
  float*  zz      = (float*)(ws + WS_ZZ);
  int*    idx     = (int*)  (ws + WS_IDX);
  int*    counts  = (int*)  (ws + WS_CNT);
  double* sums    = (double*)(ws + WS_SUM);

  hipMemsetAsync(counts, 0, 65536 + 16, stream);

  k_prep <<<512, 256, 0, stream>>>(z, emb, Ti8, Ci8, zz, ee, zt, flags);
  k_mdist<<<16384, 256, 0, stream>>>(Ti8, Ci8, M1, M2, ARG);
  k_pick <<<2048, 256, 0, stream>>>(zt, emb, zz, ee, M1, M2, ARG, flags, idx, out_idxf);
  k_scatter<<<256, 256, 0, stream>>>(z, emb, idx, out_zq, counts, sums);
  k_hist <<<64, 256, 0, stream>>>(counts, sums);
  k_final<<<1, 64, 0, stream>>>(sums, out_loss, out_perp);
}

// Round 9
// 208.685 us; speedup vs baseline: 1.6589x; 1.0631x over previous
//
#include <hip/hip_runtime.h>
#include <math.h>

#define NTOK   16384
#define DDIM   256
#define HWD    1024        // H*W per batch image
#define CHW    262144      // 256*1024 floats per batch
#define MARGIN 3.0e-4f     // i8 stat (8 sigma of est-diff) + ref d-grid + fp16 quant
#define CLIPF  5.5f
#define QS     (127.0f/5.5f)
#define EQS    2080768.0f  // 16384*127
#define SCALE  (5.5f/(127.0f*127.0f*16384.0f))   // sz*se

// ws layout (bytes)
#define WS_TI8   0u          // 4 MB  i8 token images [128 tiles][4 chunks][128 rows][64B swz]
#define WS_CI8   4194304u    // 4 MB  i8 code rows PLAIN [code][256]
#define WS_M1    8388608u    // 8 MB  fp16 min1: [n][256 subtiles]
#define WS_M2    16777216u   // 8 MB  fp16 min2: [256 subtiles][n]
#define WS_ARG   25165824u   // 4 MB  u8 argmin-in-subtile: [256 subtiles][n]
#define WS_FLG   29360128u   // 16KB per-token clip flags
#define WS_EE    29376512u   // 64KB
#define WS_ZZ    29442048u   // 64KB
#define WS_IDX   29507584u   // 64KB
#define WS_CNT   29573120u   // 64KB
#define WS_SUM   29638656u   // 16B (contiguous after counts)

typedef __attribute__((ext_vector_type(4)))  int   i32x4;
typedef __attribute__((ext_vector_type(16))) char  c16;

__device__ __forceinline__ void top2m(int& a1, int& a2, const int b1, const int b2) {
  const int mn = min(a1, b1);          // merge (a1,a2) with (b1,b2)
  a1 = max(a1, b1);
  a2 = max(max(a2, b2), mn);           // max3
}

// ---------------- fused prep: blocks 0..255 tokens, 256..511 codes ----------------
__global__ __launch_bounds__(256) void k_prep(const float* __restrict__ z,
                                              const float* __restrict__ emb,
                                              char* __restrict__ Ti8,
                                              char* __restrict__ Ci8,
                                              float* __restrict__ zz,
                                              float* __restrict__ ee,
                                              float* __restrict__ zt,
                                              unsigned char* __restrict__ flags) {
  const int bid = blockIdx.x;
  const int tid = threadIdx.x;
  const int t64 = tid & 63, chunk = tid >> 6;
  if (bid < 256) {                      // ---- token role
    __shared__ double part[4][64];
    __shared__ int   fpart[4][64];
    const int n = bid * 64 + t64;
    const int b = n >> 10, hw = n & 1023;
    const float* zp = z + (size_t)b * CHW + hw;
    float tmp[64];
    double s = 0.0;
    int clip = 0;
    #pragma unroll
    for (int j = 0; j < 64; ++j) {      // coalesced across t64 for each j
      const float f = zp[(size_t)(chunk * 64 + j) * HWD];
      tmp[j] = f;
      s += (double)f * (double)f;
      clip |= (fabsf(f) > CLIPF) ? 1 : 0;
    }
    c16 q[4];
    #pragma unroll
    for (int sl = 0; sl < 4; ++sl)
      #pragma unroll
      for (int j = 0; j < 16; ++j)
        q[sl][j] = (char)(int)rintf(fminf(fmaxf(tmp[sl * 16 + j], -CLIPF), CLIPF) * QS);
    const int rl = n & 127, tile = n >> 7;
    char* dst = Ti8 + (size_t)tile * 32768 + chunk * 8192 + rl * 64;
    const int sw = ((rl >> 1) & 3) << 4;
    #pragma unroll
    for (int sl = 0; sl < 4; ++sl) *(c16*)(dst + ((sl * 16) ^ sw)) = q[sl];
    float* ztp = zt + (size_t)n * 256 + chunk * 64;
    #pragma unroll
    for (int j4 = 0; j4 < 16; ++j4) *(float4*)(ztp + j4 * 4) = *(float4*)&tmp[j4 * 4];
    part[chunk][t64] = s;
    fpart[chunk][t64] = clip;
    __syncthreads();
    if (tid < 64) {
      zz[n] = (float)(part[0][t64] + part[1][t64] + part[2][t64] + part[3][t64]);
      flags[n] = (unsigned char)(fpart[0][t64] | fpart[1][t64] | fpart[2][t64] | fpart[3][t64]);
    }
  } else {                              // ---- code role (coalesced via LDS transpose)
    __shared__ float rows[64][257];     // +1 pad
    __shared__ double part2[4][64];
    const int k0 = (bid - 256) * 64;
    for (int i = tid; i < 16384; i += 256)
      rows[i >> 8][i & 255] = emb[(size_t)k0 * DDIM + i];
    __syncthreads();
    const int code = k0 + t64;
    double s = 0.0;
    c16 q[4];
    #pragma unroll
    for (int sl = 0; sl < 4; ++sl)
      #pragma unroll
      for (int j = 0; j < 16; ++j) {
        const float f = rows[t64][chunk * 64 + sl * 16 + j];
        q[sl][j] = (char)(int)rintf(f * EQS);   // range-safe (|e|<=1/16384 -> |q|<=127)
        s += (double)f * (double)f;
      }
    char* dst = Ci8 + (size_t)code * 256 + chunk * 64;   // PLAIN layout
    #pragma unroll
    for (int sl = 0; sl < 4; ++sl) *(c16*)(dst + sl * 16) = q[sl];
    part2[chunk][t64] = s;
    __syncthreads();
    if (tid < 64)
      ee[code] = (float)(part2[0][t64] + part2[1][t64] + part2[2][t64] + part2[3][t64]);
  }
}

// ---------------- phase-1: i8 GEMM, codes-in-VGPR, 8 token-tiles per block ----------------
// grid 2048 = 8 XCD x 16 ctile-local x 16 ttile-groups; 256 thr = 4 waves (2 code x 2 token).
// Block: ctile (128 codes, A-frags in VGPR loaded once) x 8 ttiles of 128 tokens
// (B double-buffered in LDS). Per (token, 64-code wr-subtile): branchless packed-key
// top-2 -> (min1, argmin, min2). A=codes: C row=code(fq*4+j+m*16), col=token(fr+n*16).
__global__ __launch_bounds__(256) void k_mdist(
    const char* __restrict__ tokimg, const char* __restrict__ codrows,
    _Float16* __restrict__ M1, _Float16* __restrict__ M2,
    unsigned char* __restrict__ ARG) {
  __shared__ __attribute__((aligned(16))) char ldsB[65536];   // 2 x 32KB token tiles
  __shared__ _Float16 m1l[256];
  __shared__ _Float16 m2l[256];
  __shared__ unsigned char agl[256];
  const int raw = blockIdx.x;
  const int p = raw & 7;                        // XCD
  const int ctile = p * 16 + ((raw >> 3) & 15); // 0..127
  const int tgrp = raw >> 7;                    // 0..15 (8 ttiles each)
  const int tid = threadIdx.x;
  const int w = tid >> 6, lane = tid & 63;
  const int wr = w >> 1, wc = w & 1;            // code-half, token-half
  const int fr = lane & 15, fq = lane >> 4;

  // A-frags: 64 codes x K=256 in VGPRs, loaded once from plain rows
  i32x4 afr[4][4];                              // [m][kc]
  {
    const char* ab = codrows + (size_t)(ctile * 128 + wr * 64 + fr) * 256 + fq * 16;
    #pragma unroll
    for (int m = 0; m < 4; ++m)
      #pragma unroll
      for (int kc = 0; kc < 4; ++kc)
        afr[m][kc] = *(const i32x4*)(ab + m * 16 * 256 + kc * 64);
  }

  int boff[4][4];                               // [n][kc] LDS offsets (swizzled image)
  #pragma unroll
  for (int n = 0; n < 4; ++n)
    #pragma unroll
    for (int kc = 0; kc < 4; ++kc) {
      const int t = wc * 64 + n * 16 + fr;
      boff[n][kc] = kc * 8192 + t * 64 + ((fq * 16) ^ (((t >> 1) & 3) << 4));
    }

  #define STAGEB(buf, tt)                                                             \
    {                                                                                 \
      const char* src = tokimg + (size_t)(tt) * 32768;                                \
      char* dstb = ldsB + (buf) * 32768;                                              \
      _Pragma("unroll")                                                               \
      for (int r = 0; r < 8; ++r) {                                                   \
        const int u = r * 256 + tid;                                                  \
        __builtin_amdgcn_global_load_lds(                                             \
            (const __attribute__((address_space(1))) void*)(src + u * 16),            \
            (__attribute__((address_space(3))) void*)(dstb + u * 16), 16, 0, 0);      \
      }                                                                               \
    }

  STAGEB(0, tgrp * 8);
  __syncthreads();                              // buf0 ready

  const int fq4 = fq * 4;
  for (int it = 0; it < 8; ++it) {
    const int ttile = tgrp * 8 + it;
    if (it < 7) STAGEB((it + 1) & 1, ttile + 1);     // prefetch next B
    const char* bufb = ldsB + (it & 1) * 32768;

    i32x4 acc[4][4];
    #pragma unroll
    for (int m = 0; m < 4; ++m)
      #pragma unroll
      for (int n = 0; n < 4; ++n) acc[m][n] = (i32x4)0;

    #pragma unroll
    for (int kc = 0; kc < 4; ++kc) {
      i32x4 b[4];
      #pragma unroll
      for (int n = 0; n < 4; ++n) b[n] = *(const i32x4*)(bufb + boff[n][kc]);
      #pragma unroll
      for (int m = 0; m < 4; ++m)
        #pragma unroll
        for (int n = 0; n < 4; ++n)
          acc[m][n] = __builtin_amdgcn_mfma_i32_16x16x64_i8(afr[m][kc], b[n], acc[m][n], 0, 0, 0);
    }

    // branchless packed-key top-2 per (token fr+n*16, wr-subtile)
    #pragma unroll
    for (int n = 0; n < 4; ++n) {
      int p1[8], p2[8];
      #pragma unroll
      for (int m = 0; m < 4; ++m)
        #pragma unroll
        for (int jj = 0; jj < 2; ++jj) {
          const int k0 = (acc[m][n][2 * jj]     << 8) | (m * 16 + fq4 + 2 * jj);
          const int k1 = (acc[m][n][2 * jj + 1] << 8) | (m * 16 + fq4 + 2 * jj + 1);
          p1[m * 2 + jj] = max(k0, k1);
          p2[m * 2 + jj] = min(k0, k1);
        }
      top2m(p1[0], p2[0], p1[1], p2[1]); top2m(p1[2], p2[2], p1[3], p2[3]);
      top2m(p1[4], p2[4], p1[5], p2[5]); top2m(p1[6], p2[6], p1[7], p2[7]);
      top2m(p1[0], p2[0], p1[2], p2[2]); top2m(p1[4], p2[4], p1[6], p2[6]);
      top2m(p1[0], p2[0], p1[4], p2[4]);
      int k1 = p1[0], k2 = p2[0];
      #pragma unroll
      for (int off = 16; off <= 32; off <<= 1) {
        const int o1 = __shfl_xor(k1, off, 64);
        const int o2 = __shfl_xor(k2, off, 64);
        top2m(k1, k2, o1, o2);
      }
      if (lane < 16) {
        const int tl = wc * 64 + n * 16 + fr;
        m1l[tl * 2 + wr] = (_Float16)(-2.0f * SCALE * (float)(k1 >> 8));
        m2l[tl * 2 + wr] = (_Float16)(-2.0f * SCALE * (float)(k2 >> 8));
        agl[tl * 2 + wr] = (unsigned char)(k1 & 255);
      }
    }
    __syncthreads();                    // m1l complete; stage(it+1) drained
    if (tid < 128) {
      const int tok = ttile * 128 + tid;
      *(unsigned int*)((char*)M1 + (size_t)tok * 512 + ctile * 4) =
          *(const unsigned int*)(m1l + tid * 2);
      M2[(size_t)(ctile * 2) * NTOK + tok]     = m2l[tid * 2];
      M2[(size_t)(ctile * 2 + 1) * NTOK + tok] = m2l[tid * 2 + 1];
      ARG[(size_t)(ctile * 2) * NTOK + tok]     = agl[tid * 2];
      ARG[(size_t)(ctile * 2 + 1) * NTOK + tok] = agl[tid * 2 + 1];
    }
    __syncthreads();                    // stores done; buf(it&1) free for it+2's stage
  }
}

// ---------------- phase-2: exact re-check of candidate CODES, argmin (8 tokens/block) ----------------
__global__ __launch_bounds__(256) void k_pick(
    const float* __restrict__ zt, const float* __restrict__ emb,
    const float* __restrict__ zz, const float* __restrict__ ee,
    const _Float16* __restrict__ M1, const _Float16* __restrict__ M2,
    const unsigned char* __restrict__ ARG, const unsigned char* __restrict__ flags,
    int* __restrict__ idx, float* __restrict__ out_idxf) {
  __shared__ float zrow[256];
  __shared__ int clist[2048];
  __shared__ int ccnt;
  __shared__ float wm[4];
  __shared__ unsigned long long bests[16];
  const int tid = threadIdx.x;
  const int w = tid >> 6, lane = tid & 63;
  const int g16 = lane >> 4, l16 = lane & 15;
  const int G = w * 4 + g16;              // 16 code-groups of 16 lanes
  for (int ni = 0; ni < 8; ++ni) {
    const int n = blockIdx.x * 8 + ni;
    __syncthreads();                      // protect shared reuse across tokens
    if (tid == 0) ccnt = 0;
    zrow[tid] = zt[(size_t)n * 256 + tid];
    const float ta = (float)M1[(size_t)n * 256 + tid];   // my subtile's min1
    float mr = ta;
    #pragma unroll
    for (int o = 32; o; o >>= 1) mr = fminf(mr, __shfl_xor(mr, o, 64));
    if (lane == 0) wm[w] = mr;
    __syncthreads();
    const int ex0 = flags[n];
    const float thr = ex0 ? 3.0e38f
                          : fminf(fminf(wm[0], wm[1]), fminf(wm[2], wm[3])) + MARGIN;
    if (!ex0 && ta <= thr) {              // candidate subtile tid
      const float m2v = (float)M2[(size_t)tid * NTOK + n];
      if (m2v > thr) {                    // only the argmin code can be in the window
        const int pos = atomicAdd(&ccnt, 1);
        if (pos < 2048) clist[pos] = tid * 64 + (int)ARG[(size_t)tid * NTOK + n];
      } else {                            // rare: 2+ codes in window -> whole subtile
        const int pos = atomicAdd(&ccnt, 64);
        if (pos + 64 <= 2048)
          for (int i = 0; i < 64; ++i) clist[pos + i] = tid * 64 + i;
      }
    }
    __syncthreads();
    const int doEx = ex0 || (ccnt > 2048);        // clip or overflow -> exhaustive
    const int nc = doEx ? 16384 : ccnt;
    const float zzn = zz[n];
    unsigned long long best = ~0ull;
    for (int ci = 0; ci < nc; ci += 16) {         // 16 codes in parallel
      int k;
      if (doEx) k = ci + G;
      else { const int sl = ci + G; k = clist[sl < nc ? sl : 0]; }  // dup harmless
      const float* er = emb + (size_t)k * DDIM;
      double s = 0.0;
      #pragma unroll
      for (int qq = 0; qq < 4; ++qq) {
        const float4 ev = *(const float4*)(er + qq * 64 + l16 * 4);   // coalesced 256B
        const float4 zv = *(const float4*)(&zrow[qq * 64 + l16 * 4]);
        s += (double)zv.x * (double)ev.x + (double)zv.y * (double)ev.y
           + (double)zv.z * (double)ev.z + (double)zv.w * (double)ev.w;
      }
      #pragma unroll
      for (int o = 8; o; o >>= 1) s += __shfl_xor(s, o, 16);
      if (l16 == 0) {
        const float mm = (float)s;                   // exact dot -> one fp32 rounding
        const float d = (zzn + ee[k]) - 2.0f * mm;   // replicate ref quantization (d > 0)
        const unsigned long long c =
            ((unsigned long long)__float_as_uint(d) << 32) | (unsigned int)k;
        if (c < best) best = c;                      // lexicographic (d, k)
      }
    }
    if (l16 == 0) bests[G] = best;
    __syncthreads();
    if (tid == 0) {
      unsigned long long bb = bests[0];
      #pragma unroll
      for (int i = 1; i < 16; ++i) bb = bests[i] < bb ? bests[i] : bb;
      const int k0 = (int)(bb & 0xffffffffu);
      idx[n] = k0;
      out_idxf[n] = (float)k0;
    }
  }
}

// ---------------- scatter z_q (coalesced), loss partial, counts ----------------
__global__ __launch_bounds__(256) void k_scatter(
    const float* __restrict__ z, const float* __restrict__ emb,
    const int* __restrict__ idx, float* __restrict__ out_zq,
    int* __restrict__ counts, double* __restrict__ sums) {
  __shared__ float et[64][257];   // 64 tokens x 256 dims, pad 257
  __shared__ int sidx[64];
  __shared__ double w4[4];
  const int tg = blockIdx.x;      // 256 groups of 64 tokens
  const int n0 = tg * 64;
  const int b = n0 >> 10, hw0 = n0 & 1023;
  const int tid = threadIdx.x;
  if (tid < 64) sidx[tid] = idx[n0 + tid];
  __syncthreads();
  for (int i = tid; i < 16384; i += 256) {      // gather code rows (coalesced along d)
    const int t = i >> 8, d = i & 255;
    et[t][d] = emb[(size_t)sidx[t] * DDIM + d];
  }
  __syncthreads();
  const float* zb = z + (size_t)b * CHW + hw0;
  float* ob = out_zq + (size_t)b * CHW + hw0;
  double s = 0.0;
  for (int i = tid; i < 16384; i += 256) {      // NCHW order: coalesced z reads + zq writes
    const int d = i >> 6, t = i & 63;
    const float v = et[t][d];
    const float diff = v - zb[(size_t)d * HWD + t];
    ob[(size_t)d * HWD + t] = v;                // z_q_st == z_q numerically
    s += (double)diff * (double)diff;
  }
  #pragma unroll
  for (int o = 32; o; o >>= 1) s += __shfl_xor(s, o, 64);
  const int wd = tid >> 6, lane = tid & 63;
  if (lane == 0) w4[wd] = s;
  __syncthreads();
  if (tid == 0) atomicAdd(&sums[0], w4[0] + w4[1] + w4[2] + w4[3]);
  if (tid < 64) atomicAdd(&counts[sidx[tid]], 1);
}

// ---------------- entropy partial from counts ----------------
__global__ __launch_bounds__(256) void k_hist(const int* __restrict__ counts,
                                              double* __restrict__ sums) {
  const int i = blockIdx.x * 256 + threadIdx.x;
  const float em = (float)counts[i] * (1.0f / 16384.0f);
  const float term = em * logf(em + 1e-10f);
  double s = (double)term;
  #pragma unroll
  for (int o = 32; o; o >>= 1) s += __shfl_xor(s, o, 64);
  __shared__ double w4[4];
  const int wid = threadIdx.x >> 6, lane = threadIdx.x & 63;
  if (lane == 0) w4[wid] = s;
  __syncthreads();
  if (threadIdx.x == 0) atomicAdd(&sums[1], w4[0] + w4[1] + w4[2] + w4[3]);
}

// ---------------- finals ----------------
__global__ void k_final(const double* __restrict__ sums,
                        float* __restrict__ out_loss,
                        float* __restrict__ out_perp) {
  if (threadIdx.x == 0) {
    out_loss[0] = (float)(1.25 * sums[0] / 4194304.0);  // (1+BETA)*mean
    out_perp[0] = (float)exp(-sums[1]);
  }
}

extern "C" void kernel_launch(void* const* d_in, const int* in_sizes, int n_in,
                              void* d_out, int out_size, void* d_ws, size_t ws_size,
                              hipStream_t stream) {
  const float* z   = (const float*)d_in[0];   // [16,256,32,32]
  const float* emb = (const float*)d_in[1];   // [16384,256]
  float* out      = (float*)d_out;
  float* out_zq   = out;                      // 4194304
  float* out_loss = out + 4194304;
  float* out_perp = out + 4194305;
  float* out_idxf = out + 4194306;            // 16384 (idx as float)
  float* zt       = out;                      // [n][d] fp32; dead before k_scatter overwrites

  char* ws = (char*)d_ws;
  char* Ti8 = ws + WS_TI8;
  char* Ci8 = ws + WS_CI8;
  _Float16* M1 = (_Float16*)(ws + WS_M1);
  _Float16* M2 = (_Float16*)(ws + WS_M2);
  unsigned char* ARG = (unsigned char*)(ws + WS_ARG);
  unsigned char* flags = (unsigned char*)(ws + WS_FLG);
  float*  ee      = (float*)(ws + WS_EE);
  float*  zz      = (float*)(ws + WS_ZZ);
  int*    idx     = (int*)  (ws + WS_IDX);
  int*    counts  = (int*)  (ws + WS_CNT);
  double* sums    = (double*)(ws + WS_SUM);

  hipMemsetAsync(counts, 0, 65536 + 16, stream);

  k_prep <<<512, 256, 0, stream>>>(z, emb, Ti8, Ci8, zz, ee, zt, flags);
  k_mdist<<<2048, 256, 0, stream>>>(Ti8, Ci8, M1, M2, ARG);
  k_pick <<<2048, 256, 0, stream>>>(zt, emb, zz, ee, M1, M2, ARG, flags, idx, out_idxf);
  k_scatter<<<256, 256, 0, stream>>>(z, emb, idx, out_zq, counts, sums);
  k_hist <<<64, 256, 0, stream>>>(counts, sums);
  k_final<<<1, 64, 0, stream>>>(sums, out_loss, out_perp);
}